// Round 10
// baseline (365.561 us; speedup 1.0000x reference)
//
#include <hip/hip_runtime.h>
#include <hip/hip_bf16.h>

#define TT 2048
#define DD 1024
#define FF 2048
#define NEXPI 10   // 2 shared + 8 routed expert instances
#define TCH 512    // token chunk for single-pass gemm1

typedef __attribute__((ext_vector_type(4))) int v4i;

__device__ __forceinline__ double wave_sum_d(double v) {
#pragma unroll
  for (int o = 32; o > 0; o >>= 1) v += __shfl_down(v, o);
  return v;
}
__device__ __forceinline__ double wave_max_d(double v) {
#pragma unroll
  for (int o = 32; o > 0; o >>= 1) v = fmax(v, __shfl_down(v, o));
  return v;
}

// async global->LDS, 16B per lane; lds dest is wave-uniform base, lane l lands at +l*16
__device__ __forceinline__ void gll16(const void* g, void* l) {
  __builtin_amdgcn_global_load_lds(
      (const __attribute__((address_space(1))) void*)g,
      (__attribute__((address_space(3))) void*)l, 16, 0, 0);
}

// stage ROWS x 64B tile (i8, row stride K bytes in global) into linear LDS
template<int ROWS>
__device__ __forceinline__ void stage_rows(const signed char* src, int K,
                                           signed char* lds, int tid) {
  int w = tid >> 6, l = tid & 63;
  int sub = l >> 2, seg = (l & 3) * 16;
#pragma unroll
  for (int i = 0; i < ROWS / 64; ++i) {
    int rbase = w * (ROWS / 4) + i * 16;
    gll16(src + (size_t)(rbase + sub) * K + seg, lds + rbase * 64);
  }
}

// ---------------- zero init (rowmax slots) ----------------
__global__ void k_zero(unsigned* __restrict__ rm) {
  int i = blockIdx.x * 256 + threadIdx.x;
  if (i < NEXPI * TT) rm[i] = 0u;
}

// ------------- rmsnorm + per-token absmax + int8 quant + bf16 h (f64 math) -------------
__global__ __launch_bounds__(256) void k_rms_quant(
    const float* __restrict__ x, const float* __restrict__ rw,
    signed char* __restrict__ qh, __hip_bfloat16* __restrict__ hb,
    double* __restrict__ amax_clip) {
  __shared__ double red[12];
  int t = blockIdx.x, tid = threadIdx.x;
  int lane = tid & 63, wid = tid >> 6;
  float4 xv = ((const float4*)(x + (size_t)t * DD))[tid];
  double x0 = xv.x, x1 = xv.y, x2 = xv.z, x3 = xv.w;
  double ss = x0 * x0 + x1 * x1 + x2 * x2 + x3 * x3;
  ss = wave_sum_d(ss);
  if (lane == 0) red[wid] = ss;
  __syncthreads();
  if (tid == 0) {
    double s = red[0] + red[1] + red[2] + red[3];
    red[8] = 1.0 / sqrt(s * (1.0 / DD) + 1e-6);
  }
  __syncthreads();
  double r = red[8];
  float4 wv = ((const float4*)rw)[tid];
  double h0 = x0 * r * (double)wv.x, h1 = x1 * r * (double)wv.y;
  double h2 = x2 * r * (double)wv.z, h3 = x3 * r * (double)wv.w;
  __hip_bfloat16* hp = hb + (size_t)t * DD + tid * 4;
  hp[0] = __float2bfloat16((float)h0); hp[1] = __float2bfloat16((float)h1);
  hp[2] = __float2bfloat16((float)h2); hp[3] = __float2bfloat16((float)h3);
  double am = fmax(fmax(fabs(h0), fabs(h1)), fmax(fabs(h2), fabs(h3)));
  am = wave_max_d(am);
  if (lane == 0) red[4 + wid] = am;
  __syncthreads();
  if (tid == 0) {
    double a = fmax(fmax(red[4], red[5]), fmax(red[6], red[7]));
    red[9] = fmax(a, 1e-5);
  }
  __syncthreads();
  double clipv = red[9];
  if (tid == 0) amax_clip[t] = clipv;
  double s = 127.0 / clipv;
  int q0 = (int)fmin(127.0, fmax(-128.0, rint(h0 * s)));
  int q1 = (int)fmin(127.0, fmax(-128.0, rint(h1 * s)));
  int q2 = (int)fmin(127.0, fmax(-128.0, rint(h2 * s)));
  int q3 = (int)fmin(127.0, fmax(-128.0, rint(h3 * s)));
  unsigned pw = (unsigned)(q0 & 255) | ((unsigned)(q1 & 255) << 8) |
                ((unsigned)(q2 & 255) << 16) | ((unsigned)(q3 & 255) << 24);
  *(unsigned*)(qh + (size_t)t * DD + tid * 4) = pw;
}

// ------------- weight absmean: f64 partial sums, 20 matrices x 256 blocks -------------
__global__ __launch_bounds__(256) void k_wabs_part(
    const float* __restrict__ w1s, const float* __restrict__ w2s,
    const float* __restrict__ w1r, const float* __restrict__ w2r,
    double* __restrict__ part) {
  __shared__ double red[4];
  int m = blockIdx.x >> 8, blk = blockIdx.x & 255;
  const float* base;
  if (m < 2)       base = w1s + (size_t)m * (DD * FF);
  else if (m < 4)  base = w2s + (size_t)(m - 2) * (DD * FF);
  else if (m < 12) base = w1r + (size_t)(m - 4) * (DD * FF);
  else             base = w2r + (size_t)(m - 12) * (DD * FF);
  const float4* p = (const float4*)(base + (size_t)blk * 8192);
  int tid = threadIdx.x;
  double s0 = 0.0, s1 = 0.0, s2 = 0.0, s3 = 0.0;
#pragma unroll
  for (int i = 0; i < 2; ++i) {
    float4 va = p[tid + (i * 4 + 0) * 256];
    float4 vb = p[tid + (i * 4 + 1) * 256];
    float4 vc = p[tid + (i * 4 + 2) * 256];
    float4 vd = p[tid + (i * 4 + 3) * 256];
    s0 += (double)fabsf(va.x) + (double)fabsf(va.y) + (double)fabsf(va.z) + (double)fabsf(va.w);
    s1 += (double)fabsf(vb.x) + (double)fabsf(vb.y) + (double)fabsf(vb.z) + (double)fabsf(vb.w);
    s2 += (double)fabsf(vc.x) + (double)fabsf(vc.y) + (double)fabsf(vc.z) + (double)fabsf(vc.w);
    s3 += (double)fabsf(vd.x) + (double)fabsf(vd.y) + (double)fabsf(vd.z) + (double)fabsf(vd.w);
  }
  double s = (s0 + s1) + (s2 + s3);
  s = wave_sum_d(s);
  int lane = tid & 63, wid = tid >> 6;
  if (lane == 0) red[wid] = s;
  __syncthreads();
  if (tid == 0) part[m * 256 + blk] = red[0] + red[1] + red[2] + red[3];
}

__global__ __launch_bounds__(256) void k_wscale_final(
    const double* __restrict__ part, double* __restrict__ wscale) {
  __shared__ double red[4];
  int m = blockIdx.x, tid = threadIdx.x;
  double v = part[m * 256 + tid];
  v = wave_sum_d(v);
  if ((tid & 63) == 0) red[tid >> 6] = v;
  __syncthreads();
  if (tid == 0)
    wscale[m] = (red[0] + red[1] + red[2] + red[3]) * (1.0 / 2097152.0) + 1e-8;
}

// ------------- router: bf16 products, f64 accum, bf16-rounded logits,
//               top-2 (lower-index tie-break), renorm -> dense gates -------------
__global__ __launch_bounds__(64) void k_router(
    const __hip_bfloat16* __restrict__ hb, const float* __restrict__ rw,
    float* __restrict__ gates) {
  int t = blockIdx.x, lane = threadIdx.x;
  double acc[8];
#pragma unroll
  for (int e = 0; e < 8; ++e) acc[e] = 0.0;
  const __hip_bfloat16* hp = hb + (size_t)t * DD;
  for (int d = lane; d < DD; d += 64) {
    double hv = (double)__bfloat162float(hp[d]);
#pragma unroll
    for (int e = 0; e < 8; ++e) {
      double wv = (double)__bfloat162float(__float2bfloat16(rw[e * DD + d]));
      acc[e] += hv * wv;
    }
  }
#pragma unroll
  for (int e = 0; e < 8; ++e) acc[e] = wave_sum_d(acc[e]);
  if (lane == 0) {
    double lb[8];
#pragma unroll
    for (int e = 0; e < 8; ++e)
      lb[e] = (double)__bfloat162float(__float2bfloat16((float)acc[e]));
    double mx = lb[0];
#pragma unroll
    for (int e = 1; e < 8; ++e) mx = fmax(mx, lb[e]);
    double p[8];
#pragma unroll
    for (int e = 0; e < 8; ++e) p[e] = exp(lb[e] - mx);
    int i0 = 0;
    for (int e = 1; e < 8; ++e) if (p[e] > p[i0]) i0 = e;
    int i1 = (i0 == 0) ? 1 : 0;
    for (int e = 0; e < 8; ++e) if (e != i0 && p[e] > p[i1]) i1 = e;
    double den = p[i0] + p[i1];
    float o[8] = {0.f, 0.f, 0.f, 0.f, 0.f, 0.f, 0.f, 0.f};
    o[i0] = (float)(p[i0] / den);
    o[i1] = (float)(p[i1] / den);
#pragma unroll
    for (int e = 0; e < 8; ++e) gates[(size_t)t * 8 + e] = o[e];
  }
}

// ------------- ternary quant helper (f64 bins) -------------
__device__ __forceinline__ int qtern(float v, double winv) {
  double q = rint((double)v * winv);
  return (int)fmin(1.0, fmax(-1.0, q));
}
__device__ __forceinline__ unsigned pack4(int a, int b, int c, int d) {
  return (unsigned)(a & 255) | ((unsigned)(b & 255) << 8) |
         ((unsigned)(c & 255) << 16) | ((unsigned)(d & 255) << 24);
}

// ------------- weight quant + transpose: f32 [R][C] -> i8 W^T [C][R] -------------
__global__ __launch_bounds__(256) void k_wquant(
    const float* __restrict__ w1s, const float* __restrict__ w2s,
    const float* __restrict__ w1r, const float* __restrict__ w2r,
    const double* __restrict__ wscale,
    signed char* __restrict__ q1T, signed char* __restrict__ q2T) {
  __shared__ signed char tile[64 * 68];
  int bid = blockIdx.x;
  int m = bid >> 9, t = bid & 511;
  const float* src;
  signed char* dst;
  int ld, ldo, rt, ct;
  if (m < 2) {
    src = w1s + (size_t)m * DD * FF;
    dst = q1T + (size_t)m * FF * DD;
    ld = FF; ldo = DD; rt = t >> 5; ct = t & 31;
  } else if (m < 4) {
    src = w2s + (size_t)(m - 2) * FF * DD;
    dst = q2T + (size_t)(m - 2) * DD * FF;
    ld = DD; ldo = FF; rt = t >> 4; ct = t & 15;
  } else if (m < 12) {
    src = w1r + (size_t)(m - 4) * DD * FF;
    dst = q1T + (size_t)(m - 2) * FF * DD;
    ld = FF; ldo = DD; rt = t >> 5; ct = t & 31;
  } else {
    src = w2r + (size_t)(m - 12) * FF * DD;
    dst = q2T + (size_t)(m - 10) * DD * FF;
    ld = DD; ldo = FF; rt = t >> 4; ct = t & 15;
  }
  double winv = 1.0 / wscale[m];
  int row0 = rt * 64, col0 = ct * 64;
  int r = threadIdx.x >> 2, sc_ = (threadIdx.x & 3) * 16;
  const float* sp = src + (size_t)(row0 + r) * ld + col0 + sc_;
#pragma unroll
  for (int g = 0; g < 4; ++g) {
    float4 v = *(const float4*)(sp + g * 4);
    unsigned pk = pack4(qtern(v.x, winv), qtern(v.y, winv),
                        qtern(v.z, winv), qtern(v.w, winv));
    *(unsigned*)(tile + r * 68 + sc_ + g * 4) = pk;
  }
  __syncthreads();
  int c = threadIdx.x >> 2, sr = (threadIdx.x & 3) * 16;
  unsigned o[4];
#pragma unroll
  for (int g = 0; g < 4; ++g) {
    int j = sr + g * 4;
    o[g] = pack4(tile[(j + 0) * 68 + c], tile[(j + 1) * 68 + c],
                 tile[(j + 2) * 68 + c], tile[(j + 3) * 68 + c]);
  }
  int4 ov = make_int4((int)o[0], (int)o[1], (int)o[2], (int)o[3]);
  *(int4*)(dst + (size_t)(col0 + c) * ldo + row0 + sr) = ov;
}

// ------------- scale precompute -------------
__global__ __launch_bounds__(256) void k_scales1(
    const double* __restrict__ amax_clip, const double* __restrict__ wscale,
    float* __restrict__ srow1) {
  int i = blockIdx.x * 256 + threadIdx.x;   // i = e*TT + t
  if (i >= NEXPI * TT) return;
  int e = i >> 11, t = i & (TT - 1);
  double wsc = wscale[e < 2 ? e : e + 2];
  double csc = wsc * (1.0 / 127.0);
  srow1[i] = (float)(amax_clip[t] * csc);
}

// sg2[e][t] = float(clip * wscale2[e]/127) * gate
__global__ __launch_bounds__(256) void k_scales2(
    const unsigned* __restrict__ rowmax, const double* __restrict__ wscale,
    const float* __restrict__ gates, float* __restrict__ sg2) {
  int i = blockIdx.x * 256 + threadIdx.x;
  if (i >= NEXPI * TT) return;
  int e = i >> 11, t = i & (TT - 1);
  float clip = fmaxf(__uint_as_float(rowmax[i]), 1e-5f);
  double csc = wscale[e < 2 ? e + 2 : e + 10] * (1.0 / 127.0);
  float g = (e < 2) ? 1.f : gates[(size_t)t * 8 + (e - 2)];
  sg2[i] = (float)((double)clip * csc) * g;
}

// ------------- 128x128 GEMM core: single-buffered, 2-barrier -------------
__device__ __forceinline__ void core128(
    const signed char* __restrict__ a_src, const signed char* __restrict__ b_src,
    int K, signed char* As, signed char* Bs, int tid, int lane, int wr, int wc,
    v4i acc[4][4]) {
  int kg = (lane >> 4) * 16, rsel = lane & 15;
  for (int k0 = 0; k0 < K; k0 += 64) {
    __syncthreads();
    stage_rows<128>(a_src + k0, K, As, tid);
    stage_rows<128>(b_src + k0, K, Bs, tid);
    __syncthreads();
    v4i af[4], bf[4];
#pragma unroll
    for (int mi = 0; mi < 4; ++mi)
      af[mi] = *(const v4i*)(As + (wr * 64 + mi * 16 + rsel) * 64 + kg);
#pragma unroll
    for (int ni = 0; ni < 4; ++ni)
      bf[ni] = *(const v4i*)(Bs + (wc * 64 + ni * 16 + rsel) * 64 + kg);
#pragma unroll
    for (int mi = 0; mi < 4; ++mi)
#pragma unroll
      for (int ni = 0; ni < 4; ++ni)
        acc[mi][ni] = __builtin_amdgcn_mfma_i32_16x16x64_i8(af[mi], bf[ni], acc[mi][ni], 0, 0, 0);
  }
}

// ------------- 64x128 GEMM core: single-buffered, 2-barrier -------------
__device__ __forceinline__ void core64x128(
    const signed char* __restrict__ a_src, const signed char* __restrict__ b_src,
    int K, signed char* As, signed char* Bs, int tid, int lane, int wr, int wc,
    v4i acc[2][4]) {
  int kg = (lane >> 4) * 16, rsel = lane & 15;
  for (int k0 = 0; k0 < K; k0 += 64) {
    __syncthreads();
    stage_rows<64>(a_src + k0, K, As, tid);
    stage_rows<128>(b_src + k0, K, Bs, tid);
    __syncthreads();
    v4i af[2], bf[4];
#pragma unroll
    for (int mi = 0; mi < 2; ++mi)
      af[mi] = *(const v4i*)(As + (wr * 32 + mi * 16 + rsel) * 64 + kg);
#pragma unroll
    for (int ni = 0; ni < 4; ++ni)
      bf[ni] = *(const v4i*)(Bs + (wc * 64 + ni * 16 + rsel) * 64 + kg);
#pragma unroll
    for (int mi = 0; mi < 2; ++mi)
#pragma unroll
      for (int ni = 0; ni < 4; ++ni)
        acc[mi][ni] = __builtin_amdgcn_mfma_i32_16x16x64_i8(af[mi], bf[ni], acc[mi][ni], 0, 0, 0);
  }
}

// ------------- GEMM1 (single pass, T-chunk): abuf_c = silu f32 + rowmax ------------
// grid (FF/128, TCH/128, NEXPI); abuf_c laid out [e][TCH][FF]
__global__ __launch_bounds__(256) void k_gemm1c(
    const signed char* __restrict__ qh, const signed char* __restrict__ q1T,
    const float* __restrict__ srow1, int tbase,
    float* __restrict__ abuf_c, unsigned* __restrict__ rowmax) {
  __shared__ __align__(16) signed char As[8192];
  __shared__ __align__(16) signed char Bs[8192];
  int tid = threadIdx.x, lane = tid & 63, wid = tid >> 6;
  int wr = wid >> 1, wc = wid & 1;
  int row0 = tbase + blockIdx.y * 128, col0 = blockIdx.x * 128;
  int e = blockIdx.z;
  const signed char* qw = q1T + (size_t)e * FF * DD;
  v4i zero = {0, 0, 0, 0};
  v4i acc[4][4];
#pragma unroll
  for (int i = 0; i < 4; ++i)
#pragma unroll
    for (int j = 0; j < 4; ++j) acc[i][j] = zero;
  core128(qh + (size_t)row0 * DD, qw + (size_t)col0 * DD, DD,
          As, Bs, tid, lane, wr, wc, acc);
  const float* sr = srow1 + (size_t)e * TT;
  unsigned* rme = rowmax + (size_t)e * TT;
  float* ae = abuf_c + (size_t)e * TCH * FF;
#pragma unroll
  for (int mi = 0; mi < 4; ++mi) {
#pragma unroll
    for (int rg = 0; rg < 4; ++rg) {
      int tr = row0 + wr * 64 + mi * 16 + ((lane >> 4) << 2) + rg;
      float sA = sr[tr];
      float mloc = 0.f;
#pragma unroll
      for (int ni = 0; ni < 4; ++ni) {
        int fc = col0 + wc * 64 + ni * 16 + (lane & 15);
        float a = (float)acc[mi][ni][rg] * sA;
        float v = a / (1.f + expf(-a));
        ae[(size_t)(tr - tbase) * FF + fc] = v;
        mloc = fmaxf(mloc, fabsf(v));
      }
#pragma unroll
      for (int o = 1; o < 16; o <<= 1) mloc = fmaxf(mloc, __shfl_xor(mloc, o));
      if ((lane & 15) == 0) atomicMax(rme + tr, __float_as_uint(mloc));
    }
  }
}

// ------------- aquant (T-chunk): qa = int8(round(abuf_c * 127/clip)) -------------
__global__ __launch_bounds__(256) void k_aquantc(
    const float* __restrict__ abuf_c, const unsigned* __restrict__ rowmax,
    int tbase, signed char* __restrict__ qa) {
  const int total4 = NEXPI * TCH * FF / 4;   // 2,621,440 quads
  int stride = gridDim.x * 256;
  for (int i = blockIdx.x * 256 + threadIdx.x; i < total4; i += stride) {
    int row = i >> 9;              // FF/4 = 512 quads per row; row = e*TCH + tl
    int e = row >> 9;              // TCH = 512 rows per expert
    int tl = row & (TCH - 1);
    int t = tbase + tl;
    float clip = fmaxf(__uint_as_float(rowmax[(size_t)e * TT + t]), 1e-5f);
    float s = 127.f / clip;
    float4 v = ((const float4*)abuf_c)[i];
    int q0 = (int)fminf(127.f, fmaxf(-128.f, rintf(v.x * s)));
    int q1 = (int)fminf(127.f, fmaxf(-128.f, rintf(v.y * s)));
    int q2 = (int)fminf(127.f, fmaxf(-128.f, rintf(v.z * s)));
    int q3 = (int)fminf(127.f, fmaxf(-128.f, rintf(v.w * s)));
    ((unsigned*)qa)[(size_t)e * (TT * FF / 4) + (size_t)t * (FF / 4) + (i & 511)] =
        pack4(q0, q1, q2, q3);
  }
}

// ------------- GEMM2: pbuf[z] = sum over expert pair {2z,2z+1}; grid (8,32,5) --------
__global__ __launch_bounds__(256) void k_gemm2(
    const signed char* __restrict__ qa, const signed char* __restrict__ q2T,
    const float* __restrict__ sg2, float* __restrict__ pbuf) {
  __shared__ __align__(16) signed char As[4096];
  __shared__ __align__(16) signed char Bs[8192];
  int tid = threadIdx.x, lane = tid & 63, wid = tid >> 6;
  int wr = wid >> 1, wc = wid & 1;
  int row0 = blockIdx.y * 64, col0 = blockIdx.x * 128;
  int z = blockIdx.z;
  float facc[2][4][4];
#pragma unroll
  for (int mi = 0; mi < 2; ++mi)
#pragma unroll
    for (int ni = 0; ni < 4; ++ni)
#pragma unroll
      for (int rg = 0; rg < 4; ++rg) facc[mi][ni][rg] = 0.f;

#pragma unroll
  for (int j = 0; j < 2; ++j) {
    int e = z * 2 + j;
    const signed char* ap = qa + (size_t)e * TT * FF + (size_t)row0 * FF;
    const signed char* bp = q2T + (size_t)e * DD * FF + (size_t)col0 * FF;
    v4i zero = {0, 0, 0, 0};
    v4i acc[2][4];
#pragma unroll
    for (int a = 0; a < 2; ++a)
#pragma unroll
      for (int b = 0; b < 4; ++b) acc[a][b] = zero;
    core64x128(ap, bp, FF, As, Bs, tid, lane, wr, wc, acc);
    const float* sge = sg2 + (size_t)e * TT;
#pragma unroll
    for (int mi = 0; mi < 2; ++mi) {
#pragma unroll
      for (int rg = 0; rg < 4; ++rg) {
        int tr = row0 + wr * 32 + mi * 16 + ((lane >> 4) << 2) + rg;
        float sc = sge[tr];
#pragma unroll
        for (int ni = 0; ni < 4; ++ni)
          facc[mi][ni][rg] += (float)acc[mi][ni][rg] * sc;
      }
    }
  }
  float* pz = pbuf + (size_t)z * TT * DD;
#pragma unroll
  for (int mi = 0; mi < 2; ++mi) {
#pragma unroll
    for (int rg = 0; rg < 4; ++rg) {
      int tr = row0 + wr * 32 + mi * 16 + ((lane >> 4) << 2) + rg;
#pragma unroll
      for (int ni = 0; ni < 4; ++ni) {
        int dc = col0 + wc * 64 + ni * 16 + (lane & 15);
        pz[(size_t)tr * DD + dc] = facc[mi][ni][rg];
      }
    }
  }
}

// ------------- combine: out = sum_z pbuf[z] -------------
__global__ __launch_bounds__(256) void k_combine(
    const float* __restrict__ pbuf, float* __restrict__ out) {
  int i = blockIdx.x * 256 + threadIdx.x;  // float4 index
  float4 s = ((const float4*)pbuf)[i];
#pragma unroll
  for (int z = 1; z < 5; ++z) {
    float4 v = ((const float4*)(pbuf + (size_t)z * TT * DD))[i];
    s.x += v.x; s.y += v.y; s.z += v.z; s.w += v.w;
  }
  ((float4*)out)[i] = s;
}

extern "C" void kernel_launch(void* const* d_in, const int* in_sizes, int n_in,
                              void* d_out, int out_size, void* d_ws, size_t ws_size,
                              hipStream_t stream) {
  const float* x    = (const float*)d_in[0];
  const float* rmsw = (const float*)d_in[1];
  const float* w1s  = (const float*)d_in[2];
  const float* w2s  = (const float*)d_in[3];
  const float* w1r  = (const float*)d_in[4];
  const float* w2r  = (const float*)d_in[5];
  const float* rw   = (const float*)d_in[6];
  float* out = (float*)d_out;

  char* ws = (char*)d_ws;
  // footprint identical to round 7/9 (proven): ends at 0x7E80000 ~= 132.6MB
  double* amax_clip      = (double*)(ws + 0x0000000);   // 16KB
  double* part           = (double*)(ws + 0x0004000);   // 40KB
  double* wscale         = (double*)(ws + 0x000E000);   // 160B
  float* gates           = (float*)(ws + 0x0010000);    // 64KB
  unsigned* rowmax       = (unsigned*)(ws + 0x0020000); // 80KB
  float* srow1           = (float*)(ws + 0x0034000);    // 80KB
  float* sg2             = (float*)(ws + 0x005C000);    // 80KB
  signed char* qh        = (signed char*)(ws + 0x0080000);    // 2MB
  __hip_bfloat16* hb     = (__hip_bfloat16*)(ws + 0x0280000); // 4MB
  signed char* q1T       = (signed char*)(ws + 0x0680000);    // 20MB
  signed char* q2T       = (signed char*)(ws + 0x1A80000);    // 20MB
  signed char* qa        = (signed char*)(ws + 0x2E80000);    // 40MB
  float* pbuf            = (float*)(ws + 0x5680000);          // 40MB
  float* abuf_c          = pbuf;  // alias: abuf chunks used before gemm2 writes pbuf

  k_zero<<<(NEXPI * TT + 255) / 256, 256, 0, stream>>>(rowmax);
  k_rms_quant<<<TT, 256, 0, stream>>>(x, rmsw, qh, hb, amax_clip);
  k_wabs_part<<<20 * 256, 256, 0, stream>>>(w1s, w2s, w1r, w2r, part);
  k_wscale_final<<<20, 256, 0, stream>>>(part, wscale);
  k_router<<<TT, 64, 0, stream>>>(hb, rw, gates);
  k_wquant<<<20 * 512, 256, 0, stream>>>(w1s, w2s, w1r, w2r, wscale, q1T, q2T);
  k_scales1<<<(NEXPI * TT + 255) / 256, 256, 0, stream>>>(amax_clip, wscale, srow1);

  dim3 g1(FF / 128, TCH / 128, NEXPI);
  for (int tc = 0; tc < TT / TCH; ++tc) {
    int tbase = tc * TCH;
    k_gemm1c<<<g1, 256, 0, stream>>>(qh, q1T, srow1, tbase, abuf_c, rowmax);
    k_aquantc<<<2048, 256, 0, stream>>>(abuf_c, rowmax, tbase, qa);
  }
  k_scales2<<<(NEXPI * TT + 255) / 256, 256, 0, stream>>>(rowmax, wscale, gates, sg2);
  dim3 g2(DD / 128, TT / 64, 5);
  k_gemm2<<<g2, 256, 0, stream>>>(qa, q2T, sg2, pbuf);
  k_combine<<<TT * DD / 4 / 256, 256, 0, stream>>>(pbuf, out);
}

// Round 11
// 349.973 us; speedup vs baseline: 1.0445x; 1.0445x over previous
//
#include <hip/hip_runtime.h>
#include <hip/hip_bf16.h>

#define TT 2048
#define DD 1024
#define FF 2048
#define NEXPI 10   // 2 shared + 8 routed expert instances
#define TCH 512    // token chunk for single-pass gemm1

typedef __attribute__((ext_vector_type(4))) int v4i;

__device__ __forceinline__ double wave_sum_d(double v) {
#pragma unroll
  for (int o = 32; o > 0; o >>= 1) v += __shfl_down(v, o);
  return v;
}
__device__ __forceinline__ double wave_max_d(double v) {
#pragma unroll
  for (int o = 32; o > 0; o >>= 1) v = fmax(v, __shfl_down(v, o));
  return v;
}

// async global->LDS, 16B per lane; lds dest is wave-uniform base, lane l lands at +l*16
__device__ __forceinline__ void gll16(const void* g, void* l) {
  __builtin_amdgcn_global_load_lds(
      (const __attribute__((address_space(1))) void*)g,
      (__attribute__((address_space(3))) void*)l, 16, 0, 0);
}

// stage ROWS x 64B tile (i8, row stride K bytes in global) into linear LDS
template<int ROWS>
__device__ __forceinline__ void stage_rows(const signed char* src, int K,
                                           signed char* lds, int tid) {
  int w = tid >> 6, l = tid & 63;
  int sub = l >> 2, seg = (l & 3) * 16;
#pragma unroll
  for (int i = 0; i < ROWS / 64; ++i) {
    int rbase = w * (ROWS / 4) + i * 16;
    gll16(src + (size_t)(rbase + sub) * K + seg, lds + rbase * 64);
  }
}

// ---------------- zero init (rowmax slots) ----------------
__global__ void k_zero(unsigned* __restrict__ rm) {
  int i = blockIdx.x * 256 + threadIdx.x;
  if (i < NEXPI * TT) rm[i] = 0u;
}

// ------------- rmsnorm + per-token absmax + int8 quant + bf16 h (f64 math) -------------
__global__ __launch_bounds__(256) void k_rms_quant(
    const float* __restrict__ x, const float* __restrict__ rw,
    signed char* __restrict__ qh, __hip_bfloat16* __restrict__ hb,
    double* __restrict__ amax_clip) {
  __shared__ double red[12];
  int t = blockIdx.x, tid = threadIdx.x;
  int lane = tid & 63, wid = tid >> 6;
  float4 xv = ((const float4*)(x + (size_t)t * DD))[tid];
  double x0 = xv.x, x1 = xv.y, x2 = xv.z, x3 = xv.w;
  double ss = x0 * x0 + x1 * x1 + x2 * x2 + x3 * x3;
  ss = wave_sum_d(ss);
  if (lane == 0) red[wid] = ss;
  __syncthreads();
  if (tid == 0) {
    double s = red[0] + red[1] + red[2] + red[3];
    red[8] = 1.0 / sqrt(s * (1.0 / DD) + 1e-6);
  }
  __syncthreads();
  double r = red[8];
  float4 wv = ((const float4*)rw)[tid];
  double h0 = x0 * r * (double)wv.x, h1 = x1 * r * (double)wv.y;
  double h2 = x2 * r * (double)wv.z, h3 = x3 * r * (double)wv.w;
  __hip_bfloat16* hp = hb + (size_t)t * DD + tid * 4;
  hp[0] = __float2bfloat16((float)h0); hp[1] = __float2bfloat16((float)h1);
  hp[2] = __float2bfloat16((float)h2); hp[3] = __float2bfloat16((float)h3);
  double am = fmax(fmax(fabs(h0), fabs(h1)), fmax(fabs(h2), fabs(h3)));
  am = wave_max_d(am);
  if (lane == 0) red[4 + wid] = am;
  __syncthreads();
  if (tid == 0) {
    double a = fmax(fmax(red[4], red[5]), fmax(red[6], red[7]));
    red[9] = fmax(a, 1e-5);
  }
  __syncthreads();
  double clipv = red[9];
  if (tid == 0) amax_clip[t] = clipv;
  double s = 127.0 / clipv;
  int q0 = (int)fmin(127.0, fmax(-128.0, rint(h0 * s)));
  int q1 = (int)fmin(127.0, fmax(-128.0, rint(h1 * s)));
  int q2 = (int)fmin(127.0, fmax(-128.0, rint(h2 * s)));
  int q3 = (int)fmin(127.0, fmax(-128.0, rint(h3 * s)));
  unsigned pw = (unsigned)(q0 & 255) | ((unsigned)(q1 & 255) << 8) |
                ((unsigned)(q2 & 255) << 16) | ((unsigned)(q3 & 255) << 24);
  *(unsigned*)(qh + (size_t)t * DD + tid * 4) = pw;
}

// ------------- weight absmean: f64 partial sums, 20 matrices x 512 blocks -------------
__global__ __launch_bounds__(256) void k_wabs_part(
    const float* __restrict__ w1s, const float* __restrict__ w2s,
    const float* __restrict__ w1r, const float* __restrict__ w2r,
    double* __restrict__ part) {
  __shared__ double red[4];
  int m = blockIdx.x >> 9, blk = blockIdx.x & 511;
  const float* base;
  if (m < 2)       base = w1s + (size_t)m * (DD * FF);
  else if (m < 4)  base = w2s + (size_t)(m - 2) * (DD * FF);
  else if (m < 12) base = w1r + (size_t)(m - 4) * (DD * FF);
  else             base = w2r + (size_t)(m - 12) * (DD * FF);
  const float4* p = (const float4*)(base + (size_t)blk * 4096);
  int tid = threadIdx.x;
  float4 va = p[tid];
  float4 vb = p[tid + 256];
  float4 vc = p[tid + 512];
  float4 vd = p[tid + 768];
  double s0 = (double)fabsf(va.x) + (double)fabsf(va.y) + (double)fabsf(va.z) + (double)fabsf(va.w);
  double s1 = (double)fabsf(vb.x) + (double)fabsf(vb.y) + (double)fabsf(vb.z) + (double)fabsf(vb.w);
  double s2 = (double)fabsf(vc.x) + (double)fabsf(vc.y) + (double)fabsf(vc.z) + (double)fabsf(vc.w);
  double s3 = (double)fabsf(vd.x) + (double)fabsf(vd.y) + (double)fabsf(vd.z) + (double)fabsf(vd.w);
  double s = (s0 + s1) + (s2 + s3);
  s = wave_sum_d(s);
  int lane = tid & 63, wid = tid >> 6;
  if (lane == 0) red[wid] = s;
  __syncthreads();
  if (tid == 0) part[m * 512 + blk] = red[0] + red[1] + red[2] + red[3];
}

__global__ __launch_bounds__(256) void k_wscale_final(
    const double* __restrict__ part, double* __restrict__ wscale) {
  __shared__ double red[4];
  int m = blockIdx.x, tid = threadIdx.x;
  double v = part[m * 512 + tid] + part[m * 512 + 256 + tid];
  v = wave_sum_d(v);
  if ((tid & 63) == 0) red[tid >> 6] = v;
  __syncthreads();
  if (tid == 0)
    wscale[m] = (red[0] + red[1] + red[2] + red[3]) * (1.0 / 2097152.0) + 1e-8;
}

// ------------- router: bf16 products, f64 accum, bf16-rounded logits,
//               top-2 (lower-index tie-break), renorm -> dense gates -------------
__global__ __launch_bounds__(64) void k_router(
    const __hip_bfloat16* __restrict__ hb, const float* __restrict__ rw,
    float* __restrict__ gates) {
  int t = blockIdx.x, lane = threadIdx.x;
  double acc[8];
#pragma unroll
  for (int e = 0; e < 8; ++e) acc[e] = 0.0;
  const __hip_bfloat16* hp = hb + (size_t)t * DD;
  for (int d = lane; d < DD; d += 64) {
    double hv = (double)__bfloat162float(hp[d]);
#pragma unroll
    for (int e = 0; e < 8; ++e) {
      double wv = (double)__bfloat162float(__float2bfloat16(rw[e * DD + d]));
      acc[e] += hv * wv;
    }
  }
#pragma unroll
  for (int e = 0; e < 8; ++e) acc[e] = wave_sum_d(acc[e]);
  if (lane == 0) {
    double lb[8];
#pragma unroll
    for (int e = 0; e < 8; ++e)
      lb[e] = (double)__bfloat162float(__float2bfloat16((float)acc[e]));
    double mx = lb[0];
#pragma unroll
    for (int e = 1; e < 8; ++e) mx = fmax(mx, lb[e]);
    double p[8];
#pragma unroll
    for (int e = 0; e < 8; ++e) p[e] = exp(lb[e] - mx);
    int i0 = 0;
    for (int e = 1; e < 8; ++e) if (p[e] > p[i0]) i0 = e;
    int i1 = (i0 == 0) ? 1 : 0;
    for (int e = 0; e < 8; ++e) if (e != i0 && p[e] > p[i1]) i1 = e;
    double den = p[i0] + p[i1];
    float o[8] = {0.f, 0.f, 0.f, 0.f, 0.f, 0.f, 0.f, 0.f};
    o[i0] = (float)(p[i0] / den);
    o[i1] = (float)(p[i1] / den);
#pragma unroll
    for (int e = 0; e < 8; ++e) gates[(size_t)t * 8 + e] = o[e];
  }
}

// ------------- ternary quant helper (f64 bins) -------------
__device__ __forceinline__ int qtern(float v, double winv) {
  double q = rint((double)v * winv);
  return (int)fmin(1.0, fmax(-1.0, q));
}
__device__ __forceinline__ unsigned pack4(int a, int b, int c, int d) {
  return (unsigned)(a & 255) | ((unsigned)(b & 255) << 8) |
         ((unsigned)(c & 255) << 16) | ((unsigned)(d & 255) << 24);
}

// ------------- weight quant + transpose: f32 [R][C] -> i8 W^T [C][R] -------------
__global__ __launch_bounds__(256) void k_wquant(
    const float* __restrict__ w1s, const float* __restrict__ w2s,
    const float* __restrict__ w1r, const float* __restrict__ w2r,
    const double* __restrict__ wscale,
    signed char* __restrict__ q1T, signed char* __restrict__ q2T) {
  __shared__ signed char tile[64 * 68];
  int bid = blockIdx.x;
  int m = bid >> 9, t = bid & 511;
  const float* src;
  signed char* dst;
  int ld, ldo, rt, ct;
  if (m < 2) {
    src = w1s + (size_t)m * DD * FF;
    dst = q1T + (size_t)m * FF * DD;
    ld = FF; ldo = DD; rt = t >> 5; ct = t & 31;
  } else if (m < 4) {
    src = w2s + (size_t)(m - 2) * FF * DD;
    dst = q2T + (size_t)(m - 2) * DD * FF;
    ld = DD; ldo = FF; rt = t >> 4; ct = t & 15;
  } else if (m < 12) {
    src = w1r + (size_t)(m - 4) * DD * FF;
    dst = q1T + (size_t)(m - 2) * FF * DD;
    ld = FF; ldo = DD; rt = t >> 5; ct = t & 31;
  } else {
    src = w2r + (size_t)(m - 12) * FF * DD;
    dst = q2T + (size_t)(m - 10) * DD * FF;
    ld = DD; ldo = FF; rt = t >> 4; ct = t & 15;
  }
  double winv = 1.0 / wscale[m];
  int row0 = rt * 64, col0 = ct * 64;
  int r = threadIdx.x >> 2, sc_ = (threadIdx.x & 3) * 16;
  const float* sp = src + (size_t)(row0 + r) * ld + col0 + sc_;
#pragma unroll
  for (int g = 0; g < 4; ++g) {
    float4 v = *(const float4*)(sp + g * 4);
    unsigned pk = pack4(qtern(v.x, winv), qtern(v.y, winv),
                        qtern(v.z, winv), qtern(v.w, winv));
    *(unsigned*)(tile + r * 68 + sc_ + g * 4) = pk;
  }
  __syncthreads();
  int c = threadIdx.x >> 2, sr = (threadIdx.x & 3) * 16;
  unsigned o[4];
#pragma unroll
  for (int g = 0; g < 4; ++g) {
    int j = sr + g * 4;
    o[g] = pack4(tile[(j + 0) * 68 + c], tile[(j + 1) * 68 + c],
                 tile[(j + 2) * 68 + c], tile[(j + 3) * 68 + c]);
  }
  int4 ov = make_int4((int)o[0], (int)o[1], (int)o[2], (int)o[3]);
  *(int4*)(dst + (size_t)(col0 + c) * ldo + row0 + sr) = ov;
}

// ------------- scale precompute -------------
__global__ __launch_bounds__(256) void k_scales1(
    const double* __restrict__ amax_clip, const double* __restrict__ wscale,
    float* __restrict__ srow1) {
  int i = blockIdx.x * 256 + threadIdx.x;   // i = e*TT + t
  if (i >= NEXPI * TT) return;
  int e = i >> 11, t = i & (TT - 1);
  double wsc = wscale[e < 2 ? e : e + 2];
  double csc = wsc * (1.0 / 127.0);
  srow1[i] = (float)(amax_clip[t] * csc);
}

// sg2[e][t] = float(clip * wscale2[e]/127) * gate
__global__ __launch_bounds__(256) void k_scales2(
    const unsigned* __restrict__ rowmax, const double* __restrict__ wscale,
    const float* __restrict__ gates, float* __restrict__ sg2) {
  int i = blockIdx.x * 256 + threadIdx.x;
  if (i >= NEXPI * TT) return;
  int e = i >> 11, t = i & (TT - 1);
  float clip = fmaxf(__uint_as_float(rowmax[i]), 1e-5f);
  double csc = wscale[e < 2 ? e + 2 : e + 10] * (1.0 / 127.0);
  float g = (e < 2) ? 1.f : gates[(size_t)t * 8 + (e - 2)];
  sg2[i] = (float)((double)clip * csc) * g;
}

// ------------- 128x128 GEMM core: single-buffered, 2-barrier -------------
__device__ __forceinline__ void core128(
    const signed char* __restrict__ a_src, const signed char* __restrict__ b_src,
    int K, signed char* As, signed char* Bs, int tid, int lane, int wr, int wc,
    v4i acc[4][4]) {
  int kg = (lane >> 4) * 16, rsel = lane & 15;
  for (int k0 = 0; k0 < K; k0 += 64) {
    __syncthreads();
    stage_rows<128>(a_src + k0, K, As, tid);
    stage_rows<128>(b_src + k0, K, Bs, tid);
    __syncthreads();
    v4i af[4], bf[4];
#pragma unroll
    for (int mi = 0; mi < 4; ++mi)
      af[mi] = *(const v4i*)(As + (wr * 64 + mi * 16 + rsel) * 64 + kg);
#pragma unroll
    for (int ni = 0; ni < 4; ++ni)
      bf[ni] = *(const v4i*)(Bs + (wc * 64 + ni * 16 + rsel) * 64 + kg);
#pragma unroll
    for (int mi = 0; mi < 4; ++mi)
#pragma unroll
      for (int ni = 0; ni < 4; ++ni)
        acc[mi][ni] = __builtin_amdgcn_mfma_i32_16x16x64_i8(af[mi], bf[ni], acc[mi][ni], 0, 0, 0);
  }
}

// ------------- 64x128 GEMM core: single-buffered, 2-barrier -------------
__device__ __forceinline__ void core64x128(
    const signed char* __restrict__ a_src, const signed char* __restrict__ b_src,
    int K, signed char* As, signed char* Bs, int tid, int lane, int wr, int wc,
    v4i acc[2][4]) {
  int kg = (lane >> 4) * 16, rsel = lane & 15;
  for (int k0 = 0; k0 < K; k0 += 64) {
    __syncthreads();
    stage_rows<64>(a_src + k0, K, As, tid);
    stage_rows<128>(b_src + k0, K, Bs, tid);
    __syncthreads();
    v4i af[2], bf[4];
#pragma unroll
    for (int mi = 0; mi < 2; ++mi)
      af[mi] = *(const v4i*)(As + (wr * 32 + mi * 16 + rsel) * 64 + kg);
#pragma unroll
    for (int ni = 0; ni < 4; ++ni)
      bf[ni] = *(const v4i*)(Bs + (wc * 64 + ni * 16 + rsel) * 64 + kg);
#pragma unroll
    for (int mi = 0; mi < 2; ++mi)
#pragma unroll
      for (int ni = 0; ni < 4; ++ni)
        acc[mi][ni] = __builtin_amdgcn_mfma_i32_16x16x64_i8(af[mi], bf[ni], acc[mi][ni], 0, 0, 0);
  }
}

// ------------- GEMM1 (single pass, T-chunk): abuf_c = silu f32 + rowmax ------------
// grid (FF/128, TCH/128, NEXPI); abuf_c laid out [e][TCH][FF]
__global__ __launch_bounds__(256) void k_gemm1c(
    const signed char* __restrict__ qh, const signed char* __restrict__ q1T,
    const float* __restrict__ srow1, int tbase,
    float* __restrict__ abuf_c, unsigned* __restrict__ rowmax) {
  __shared__ __align__(16) signed char As[8192];
  __shared__ __align__(16) signed char Bs[8192];
  int tid = threadIdx.x, lane = tid & 63, wid = tid >> 6;
  int wr = wid >> 1, wc = wid & 1;
  int row0 = tbase + blockIdx.y * 128, col0 = blockIdx.x * 128;
  int e = blockIdx.z;
  const signed char* qw = q1T + (size_t)e * FF * DD;
  v4i zero = {0, 0, 0, 0};
  v4i acc[4][4];
#pragma unroll
  for (int i = 0; i < 4; ++i)
#pragma unroll
    for (int j = 0; j < 4; ++j) acc[i][j] = zero;
  core128(qh + (size_t)row0 * DD, qw + (size_t)col0 * DD, DD,
          As, Bs, tid, lane, wr, wc, acc);
  const float* sr = srow1 + (size_t)e * TT;
  unsigned* rme = rowmax + (size_t)e * TT;
  float* ae = abuf_c + (size_t)e * TCH * FF;
#pragma unroll
  for (int mi = 0; mi < 4; ++mi) {
#pragma unroll
    for (int rg = 0; rg < 4; ++rg) {
      int tr = row0 + wr * 64 + mi * 16 + ((lane >> 4) << 2) + rg;
      float sA = sr[tr];
      float mloc = 0.f;
#pragma unroll
      for (int ni = 0; ni < 4; ++ni) {
        int fc = col0 + wc * 64 + ni * 16 + (lane & 15);
        float a = (float)acc[mi][ni][rg] * sA;
        float v = a / (1.f + expf(-a));
        ae[(size_t)(tr - tbase) * FF + fc] = v;
        mloc = fmaxf(mloc, fabsf(v));
      }
#pragma unroll
      for (int o = 1; o < 16; o <<= 1) mloc = fmaxf(mloc, __shfl_xor(mloc, o));
      if ((lane & 15) == 0) atomicMax(rme + tr, __float_as_uint(mloc));
    }
  }
}

// ------------- aquant (T-chunk): qa = int8(round(abuf_c * 127/clip)) -------------
__global__ __launch_bounds__(256) void k_aquantc(
    const float* __restrict__ abuf_c, const unsigned* __restrict__ rowmax,
    int tbase, signed char* __restrict__ qa) {
  const int total4 = NEXPI * TCH * FF / 4;   // 2,621,440 quads
  int stride = gridDim.x * 256;
  for (int i = blockIdx.x * 256 + threadIdx.x; i < total4; i += stride) {
    int row = i >> 9;              // FF/4 = 512 quads per row; row = e*TCH + tl
    int e = row >> 9;              // TCH = 512 rows per expert
    int tl = row & (TCH - 1);
    int t = tbase + tl;
    float clip = fmaxf(__uint_as_float(rowmax[(size_t)e * TT + t]), 1e-5f);
    float s = 127.f / clip;
    float4 v = ((const float4*)abuf_c)[i];
    int q0 = (int)fminf(127.f, fmaxf(-128.f, rintf(v.x * s)));
    int q1 = (int)fminf(127.f, fmaxf(-128.f, rintf(v.y * s)));
    int q2 = (int)fminf(127.f, fmaxf(-128.f, rintf(v.z * s)));
    int q3 = (int)fminf(127.f, fmaxf(-128.f, rintf(v.w * s)));
    ((unsigned*)qa)[(size_t)e * (TT * FF / 4) + (size_t)t * (FF / 4) + (i & 511)] =
        pack4(q0, q1, q2, q3);
  }
}

// ------------- GEMM2: pbuf[z] = sum over expert pair {2z,2z+1} ----------------------
// logical grid (8,32,5), 64x128 tiles, bijective XCD-chunk swizzle (1280 % 8 == 0)
__global__ __launch_bounds__(256) void k_gemm2(
    const signed char* __restrict__ qa, const signed char* __restrict__ q2T,
    const float* __restrict__ sg2, float* __restrict__ pbuf) {
  __shared__ __align__(16) signed char As[4096];
  __shared__ __align__(16) signed char Bs[8192];
  int lid = blockIdx.x + 8 * blockIdx.y + 256 * blockIdx.z;   // 0..1279
  int nid = (lid & 7) * 160 + (lid >> 3);                     // XCD-contiguous chunks
  int z = nid >> 8, rr = nid & 255;
  int row0 = (rr >> 3) * 64, col0 = (rr & 7) * 128;
  int tid = threadIdx.x, lane = tid & 63, wid = tid >> 6;
  int wr = wid >> 1, wc = wid & 1;
  float facc[2][4][4];
#pragma unroll
  for (int mi = 0; mi < 2; ++mi)
#pragma unroll
    for (int ni = 0; ni < 4; ++ni)
#pragma unroll
      for (int rg = 0; rg < 4; ++rg) facc[mi][ni][rg] = 0.f;

#pragma unroll
  for (int j = 0; j < 2; ++j) {
    int e = z * 2 + j;
    const signed char* ap = qa + (size_t)e * TT * FF + (size_t)row0 * FF;
    const signed char* bp = q2T + (size_t)e * DD * FF + (size_t)col0 * FF;
    v4i zero = {0, 0, 0, 0};
    v4i acc[2][4];
#pragma unroll
    for (int a = 0; a < 2; ++a)
#pragma unroll
      for (int b = 0; b < 4; ++b) acc[a][b] = zero;
    core64x128(ap, bp, FF, As, Bs, tid, lane, wr, wc, acc);
    const float* sge = sg2 + (size_t)e * TT;
#pragma unroll
    for (int mi = 0; mi < 2; ++mi) {
#pragma unroll
      for (int rg = 0; rg < 4; ++rg) {
        int tr = row0 + wr * 32 + mi * 16 + ((lane >> 4) << 2) + rg;
        float sc = sge[tr];
#pragma unroll
        for (int ni = 0; ni < 4; ++ni)
          facc[mi][ni][rg] += (float)acc[mi][ni][rg] * sc;
      }
    }
    __syncthreads();
  }
  float* pz = pbuf + (size_t)z * TT * DD;
#pragma unroll
  for (int mi = 0; mi < 2; ++mi) {
#pragma unroll
    for (int rg = 0; rg < 4; ++rg) {
      int tr = row0 + wr * 32 + mi * 16 + ((lane >> 4) << 2) + rg;
#pragma unroll
      for (int ni = 0; ni < 4; ++ni) {
        int dc = col0 + wc * 64 + ni * 16 + (lane & 15);
        pz[(size_t)tr * DD + dc] = facc[mi][ni][rg];
      }
    }
  }
}

// ------------- combine: out = sum_z pbuf[z] -------------
__global__ __launch_bounds__(256) void k_combine(
    const float* __restrict__ pbuf, float* __restrict__ out) {
  int i = blockIdx.x * 256 + threadIdx.x;  // float4 index
  float4 s = ((const float4*)pbuf)[i];
#pragma unroll
  for (int z = 1; z < 5; ++z) {
    float4 v = ((const float4*)(pbuf + (size_t)z * TT * DD))[i];
    s.x += v.x; s.y += v.y; s.z += v.z; s.w += v.w;
  }
  ((float4*)out)[i] = s;
}

extern "C" void kernel_launch(void* const* d_in, const int* in_sizes, int n_in,
                              void* d_out, int out_size, void* d_ws, size_t ws_size,
                              hipStream_t stream) {
  const float* x    = (const float*)d_in[0];
  const float* rmsw = (const float*)d_in[1];
  const float* w1s  = (const float*)d_in[2];
  const float* w2s  = (const float*)d_in[3];
  const float* w1r  = (const float*)d_in[4];
  const float* w2r  = (const float*)d_in[5];
  const float* rw   = (const float*)d_in[6];
  float* out = (float*)d_out;

  char* ws = (char*)d_ws;
  // footprint identical to round 7/9/10 (proven): ends at 0x7E80000 ~= 132.6MB
  double* amax_clip      = (double*)(ws + 0x0000000);   // 16KB
  double* part           = (double*)(ws + 0x0004000);   // 80KB (20*512 f64)
  double* wscale         = (double*)(ws + 0x0018000);   // 160B
  float* gates           = (float*)(ws + 0x0019000);    // 64KB
  unsigned* rowmax       = (unsigned*)(ws + 0x0029000); // 80KB
  float* srow1           = (float*)(ws + 0x003D000);    // 80KB
  float* sg2             = (float*)(ws + 0x0051000);    // 80KB
  signed char* qh        = (signed char*)(ws + 0x0080000);    // 2MB
  __hip_bfloat16* hb     = (__hip_bfloat16*)(ws + 0x0280000); // 4MB
  signed char* q1T       = (signed char*)(ws + 0x0680000);    // 20MB
  signed char* q2T       = (signed char*)(ws + 0x1A80000);    // 20MB
  signed char* qa        = (signed char*)(ws + 0x2E80000);    // 40MB
  float* pbuf            = (float*)(ws + 0x5680000);          // 40MB
  float* abuf_c          = pbuf;  // alias: abuf chunks used before gemm2 writes pbuf

  k_zero<<<(NEXPI * TT + 255) / 256, 256, 0, stream>>>(rowmax);
  k_rms_quant<<<TT, 256, 0, stream>>>(x, rmsw, qh, hb, amax_clip);
  k_wabs_part<<<20 * 512, 256, 0, stream>>>(w1s, w2s, w1r, w2r, part);
  k_wscale_final<<<20, 256, 0, stream>>>(part, wscale);
  k_router<<<TT, 64, 0, stream>>>(hb, rw, gates);
  k_wquant<<<20 * 512, 256, 0, stream>>>(w1s, w2s, w1r, w2r, wscale, q1T, q2T);
  k_scales1<<<(NEXPI * TT + 255) / 256, 256, 0, stream>>>(amax_clip, wscale, srow1);

  dim3 g1(FF / 128, TCH / 128, NEXPI);
  for (int tc = 0; tc < TT / TCH; ++tc) {
    int tbase = tc * TCH;
    k_gemm1c<<<g1, 256, 0, stream>>>(qh, q1T, srow1, tbase, abuf_c, rowmax);
    k_aquantc<<<2048, 256, 0, stream>>>(abuf_c, rowmax, tbase, qa);
  }
  k_scales2<<<(NEXPI * TT + 255) / 256, 256, 0, stream>>>(rowmax, wscale, gates, sg2);
  dim3 g2(8, 32, 5);
  k_gemm2<<<g2, 256, 0, stream>>>(qa, q2T, sg2, pbuf);
  k_combine<<<TT * DD / 4 / 256, 256, 0, stream>>>(pbuf, out);
}

// Round 12
// 266.870 us; speedup vs baseline: 1.3698x; 1.3114x over previous
//
#include <hip/hip_runtime.h>
#include <hip/hip_bf16.h>

#define TT 2048
#define DD 1024
#define FF 2048
#define NEXPI 10     // 2 shared + 8 routed expert instances
#define NRMAX 9216   // max compact rows: 4096 shared + 4096 routed + <=1024 pad
#define NTILEMAX 72  // NRMAX/128
#define CHTILES 36   // row-tiles per gemm1 chunk
#define CHROWS (CHTILES * 128)

typedef __attribute__((ext_vector_type(4))) int v4i;

__device__ __forceinline__ double wave_sum_d(double v) {
#pragma unroll
  for (int o = 32; o > 0; o >>= 1) v += __shfl_down(v, o);
  return v;
}
__device__ __forceinline__ double wave_max_d(double v) {
#pragma unroll
  for (int o = 32; o > 0; o >>= 1) v = fmax(v, __shfl_down(v, o));
  return v;
}

// async global->LDS, 16B per lane; lds dest is wave-uniform base, lane l lands at +l*16
__device__ __forceinline__ void gll16(const void* g, void* l) {
  __builtin_amdgcn_global_load_lds(
      (const __attribute__((address_space(1))) void*)g,
      (__attribute__((address_space(3))) void*)l, 16, 0, 0);
}

// stage ROWS x 64B tile (i8, row stride K bytes in global) into linear LDS
template<int ROWS>
__device__ __forceinline__ void stage_rows(const signed char* src, int K,
                                           signed char* lds, int tid) {
  int w = tid >> 6, l = tid & 63;
  int sub = l >> 2, seg = (l & 3) * 16;
#pragma unroll
  for (int i = 0; i < ROWS / 64; ++i) {
    int rbase = w * (ROWS / 4) + i * 16;
    gll16(src + (size_t)(rbase + sub) * K + seg, lds + rbase * 64);
  }
}

// ---------------- zero init (compact rowmax) ----------------
__global__ void k_zero(unsigned* __restrict__ rm) {
  int i = blockIdx.x * 256 + threadIdx.x;
  if (i < NRMAX) rm[i] = 0u;
}

// ------------- rmsnorm + per-token absmax + int8 quant + bf16 h (f64 math) -------------
__global__ __launch_bounds__(256) void k_rms_quant(
    const float* __restrict__ x, const float* __restrict__ rw,
    signed char* __restrict__ qh, __hip_bfloat16* __restrict__ hb,
    double* __restrict__ amax_clip) {
  __shared__ double red[12];
  int t = blockIdx.x, tid = threadIdx.x;
  int lane = tid & 63, wid = tid >> 6;
  float4 xv = ((const float4*)(x + (size_t)t * DD))[tid];
  double x0 = xv.x, x1 = xv.y, x2 = xv.z, x3 = xv.w;
  double ss = x0 * x0 + x1 * x1 + x2 * x2 + x3 * x3;
  ss = wave_sum_d(ss);
  if (lane == 0) red[wid] = ss;
  __syncthreads();
  if (tid == 0) {
    double s = red[0] + red[1] + red[2] + red[3];
    red[8] = 1.0 / sqrt(s * (1.0 / DD) + 1e-6);
  }
  __syncthreads();
  double r = red[8];
  float4 wv = ((const float4*)rw)[tid];
  double h0 = x0 * r * (double)wv.x, h1 = x1 * r * (double)wv.y;
  double h2 = x2 * r * (double)wv.z, h3 = x3 * r * (double)wv.w;
  __hip_bfloat16* hp = hb + (size_t)t * DD + tid * 4;
  hp[0] = __float2bfloat16((float)h0); hp[1] = __float2bfloat16((float)h1);
  hp[2] = __float2bfloat16((float)h2); hp[3] = __float2bfloat16((float)h3);
  double am = fmax(fmax(fabs(h0), fabs(h1)), fmax(fabs(h2), fabs(h3)));
  am = wave_max_d(am);
  if (lane == 0) red[4 + wid] = am;
  __syncthreads();
  if (tid == 0) {
    double a = fmax(fmax(red[4], red[5]), fmax(red[6], red[7]));
    red[9] = fmax(a, 1e-5);
  }
  __syncthreads();
  double clipv = red[9];
  if (tid == 0) amax_clip[t] = clipv;
  double s = 127.0 / clipv;
  int q0 = (int)fmin(127.0, fmax(-128.0, rint(h0 * s)));
  int q1 = (int)fmin(127.0, fmax(-128.0, rint(h1 * s)));
  int q2 = (int)fmin(127.0, fmax(-128.0, rint(h2 * s)));
  int q3 = (int)fmin(127.0, fmax(-128.0, rint(h3 * s)));
  unsigned pw = (unsigned)(q0 & 255) | ((unsigned)(q1 & 255) << 8) |
                ((unsigned)(q2 & 255) << 16) | ((unsigned)(q3 & 255) << 24);
  *(unsigned*)(qh + (size_t)t * DD + tid * 4) = pw;
}

// ------------- weight absmean: f64 partial sums, 20 matrices x 512 blocks -------------
__global__ __launch_bounds__(256) void k_wabs_part(
    const float* __restrict__ w1s, const float* __restrict__ w2s,
    const float* __restrict__ w1r, const float* __restrict__ w2r,
    double* __restrict__ part) {
  __shared__ double red[4];
  int m = blockIdx.x >> 9, blk = blockIdx.x & 511;
  const float* base;
  if (m < 2)       base = w1s + (size_t)m * (DD * FF);
  else if (m < 4)  base = w2s + (size_t)(m - 2) * (DD * FF);
  else if (m < 12) base = w1r + (size_t)(m - 4) * (DD * FF);
  else             base = w2r + (size_t)(m - 12) * (DD * FF);
  const float4* p = (const float4*)(base + (size_t)blk * 4096);
  int tid = threadIdx.x;
  float4 va = p[tid];
  float4 vb = p[tid + 256];
  float4 vc = p[tid + 512];
  float4 vd = p[tid + 768];
  double s0 = (double)fabsf(va.x) + (double)fabsf(va.y) + (double)fabsf(va.z) + (double)fabsf(va.w);
  double s1 = (double)fabsf(vb.x) + (double)fabsf(vb.y) + (double)fabsf(vb.z) + (double)fabsf(vb.w);
  double s2 = (double)fabsf(vc.x) + (double)fabsf(vc.y) + (double)fabsf(vc.z) + (double)fabsf(vc.w);
  double s3 = (double)fabsf(vd.x) + (double)fabsf(vd.y) + (double)fabsf(vd.z) + (double)fabsf(vd.w);
  double s = (s0 + s1) + (s2 + s3);
  s = wave_sum_d(s);
  int lane = tid & 63, wid = tid >> 6;
  if (lane == 0) red[wid] = s;
  __syncthreads();
  if (tid == 0) part[m * 512 + blk] = red[0] + red[1] + red[2] + red[3];
}

__global__ __launch_bounds__(256) void k_wscale_final(
    const double* __restrict__ part, double* __restrict__ wscale) {
  __shared__ double red[4];
  int m = blockIdx.x, tid = threadIdx.x;
  double v = part[m * 512 + tid] + part[m * 512 + 256 + tid];
  v = wave_sum_d(v);
  if ((tid & 63) == 0) red[tid >> 6] = v;
  __syncthreads();
  if (tid == 0)
    wscale[m] = (red[0] + red[1] + red[2] + red[3]) * (1.0 / 2097152.0) + 1e-8;
}

// ------------- router: bf16 products, f64 accum, bf16-rounded logits,
//               top-2 (lower-index tie-break), renorm -> dense gates + (i0,i1) ---------
__global__ __launch_bounds__(64) void k_router(
    const __hip_bfloat16* __restrict__ hb, const float* __restrict__ rw,
    float* __restrict__ gates, int2* __restrict__ i01) {
  int t = blockIdx.x, lane = threadIdx.x;
  double acc[8];
#pragma unroll
  for (int e = 0; e < 8; ++e) acc[e] = 0.0;
  const __hip_bfloat16* hp = hb + (size_t)t * DD;
  for (int d = lane; d < DD; d += 64) {
    double hv = (double)__bfloat162float(hp[d]);
#pragma unroll
    for (int e = 0; e < 8; ++e) {
      double wv = (double)__bfloat162float(__float2bfloat16(rw[e * DD + d]));
      acc[e] += hv * wv;
    }
  }
#pragma unroll
  for (int e = 0; e < 8; ++e) acc[e] = wave_sum_d(acc[e]);
  if (lane == 0) {
    double lb[8];
#pragma unroll
    for (int e = 0; e < 8; ++e)
      lb[e] = (double)__bfloat162float(__float2bfloat16((float)acc[e]));
    double mx = lb[0];
#pragma unroll
    for (int e = 1; e < 8; ++e) mx = fmax(mx, lb[e]);
    double p[8];
#pragma unroll
    for (int e = 0; e < 8; ++e) p[e] = exp(lb[e] - mx);
    int i0 = 0;
    for (int e = 1; e < 8; ++e) if (p[e] > p[i0]) i0 = e;
    int i1 = (i0 == 0) ? 1 : 0;
    for (int e = 0; e < 8; ++e) if (e != i0 && p[e] > p[i1]) i1 = e;
    double den = p[i0] + p[i1];
    float o[8] = {0.f, 0.f, 0.f, 0.f, 0.f, 0.f, 0.f, 0.f};
    o[i0] = (float)(p[i0] / den);
    o[i1] = (float)(p[i1] / den);
#pragma unroll
    for (int e = 0; e < 8; ++e) gates[(size_t)t * 8 + e] = o[e];
    i01[t] = make_int2(i0, i1);
  }
}

// ------------- per-expert ordered token lists (ballot prefix compaction) ---------------
__global__ __launch_bounds__(64) void k_lists(
    const int2* __restrict__ i01, int* __restrict__ lists,
    unsigned char* __restrict__ slots, int* __restrict__ cnt) {
  int e = blockIdx.x, lane = threadIdx.x;
  int* le = lists + e * TT;
  unsigned char* se = slots + e * TT;
  int base = 0;
  for (int it = 0; it < TT / 64; ++it) {
    int t = it * 64 + lane;
    int2 r = i01[t];
    bool hit0 = (r.x == e), hit1 = (r.y == e);
    bool hit = hit0 || hit1;
    unsigned long long m = __ballot(hit);
    int pos = base + __popcll(m & ((1ull << lane) - 1ull));
    if (hit) { le[pos] = t; se[pos] = hit0 ? 0 : 1; }
    base += __popcll(m);
  }
  if (lane == 0) cnt[e] = base;
}

// ------------- meta: segment offsets, tile->expert map, per-row gather tables ----------
__global__ __launch_bounds__(256) void k_meta(
    const int* __restrict__ cnt, const int* __restrict__ lists,
    const unsigned char* __restrict__ slots, const double* __restrict__ amax_clip,
    const double* __restrict__ wscale, int* __restrict__ meta,
    int* __restrict__ rowexp, int* __restrict__ tokidx,
    int* __restrict__ wrow, float* __restrict__ srow1c) {
  __shared__ int segs[9];
  __shared__ int scnt[8];
  int tid = threadIdx.x;
  if (tid == 0) {
    int acc = 0;
    for (int e = 0; e < 8; ++e) {
      scnt[e] = cnt[e];
      segs[e] = acc;
      acc += (cnt[e] + 127) & ~127;
    }
    segs[8] = acc;
    meta[0] = 32 + acc / 128;   // total row-tiles
    meta[1] = 4096 + acc;       // total compact rows
  }
  __syncthreads();
  int ntile = 32 + segs[8] / 128;
  for (int j = tid; j < NTILEMAX; j += 256) {
    int ei = -1;
    if (j < 16) ei = 0;
    else if (j < 32) ei = 1;
    else if (j < ntile) {
      int rr = (j - 32) * 128;
      for (int e = 0; e < 8; ++e)
        if (rr >= segs[e] && rr < segs[e + 1]) { ei = 2 + e; break; }
    }
    rowexp[j] = ei;
  }
  for (int r = tid; r < NRMAX; r += 256) {
    int t = 0; float s1 = 0.f; int w = -1;
    if (r < 4096) {
      int e = r >> 11; t = r & (TT - 1);
      double csc = wscale[e] * (1.0 / 127.0);
      s1 = (float)(amax_clip[t] * csc);
      w = e * TT + t;
    } else {
      int rr = r - 4096;
      if (rr < segs[8]) {
        int e = 0;
        for (int q = 0; q < 8; ++q)
          if (rr >= segs[q] && rr < segs[q + 1]) { e = q; break; }
        int k = rr - segs[e];
        if (k < scnt[e]) {
          t = lists[e * TT + k];
          int sl = slots[e * TT + k];
          double csc = wscale[4 + e] * (1.0 / 127.0);
          s1 = (float)(amax_clip[t] * csc);
          w = (2 + sl) * TT + t;
        }
      }
    }
    tokidx[r] = t; srow1c[r] = s1; wrow[r] = w;
  }
}

// ------------- ternary quant helper (f64 bins) -------------
__device__ __forceinline__ int qtern(float v, double winv) {
  double q = rint((double)v * winv);
  return (int)fmin(1.0, fmax(-1.0, q));
}
__device__ __forceinline__ unsigned pack4(int a, int b, int c, int d) {
  return (unsigned)(a & 255) | ((unsigned)(b & 255) << 8) |
         ((unsigned)(c & 255) << 16) | ((unsigned)(d & 255) << 24);
}

// ------------- weight quant + transpose: f32 [R][C] -> i8 W^T [C][R] -------------
__global__ __launch_bounds__(256) void k_wquant(
    const float* __restrict__ w1s, const float* __restrict__ w2s,
    const float* __restrict__ w1r, const float* __restrict__ w2r,
    const double* __restrict__ wscale,
    signed char* __restrict__ q1T, signed char* __restrict__ q2T) {
  __shared__ signed char tile[64 * 68];
  int bid = blockIdx.x;
  int m = bid >> 9, t = bid & 511;
  const float* src;
  signed char* dst;
  int ld, ldo, rt, ct;
  if (m < 2) {
    src = w1s + (size_t)m * DD * FF;
    dst = q1T + (size_t)m * FF * DD;
    ld = FF; ldo = DD; rt = t >> 5; ct = t & 31;
  } else if (m < 4) {
    src = w2s + (size_t)(m - 2) * FF * DD;
    dst = q2T + (size_t)(m - 2) * DD * FF;
    ld = DD; ldo = FF; rt = t >> 4; ct = t & 15;
  } else if (m < 12) {
    src = w1r + (size_t)(m - 4) * DD * FF;
    dst = q1T + (size_t)(m - 2) * FF * DD;
    ld = FF; ldo = DD; rt = t >> 5; ct = t & 31;
  } else {
    src = w2r + (size_t)(m - 12) * FF * DD;
    dst = q2T + (size_t)(m - 10) * DD * FF;
    ld = DD; ldo = FF; rt = t >> 4; ct = t & 15;
  }
  double winv = 1.0 / wscale[m];
  int row0 = rt * 64, col0 = ct * 64;
  int r = threadIdx.x >> 2, sc_ = (threadIdx.x & 3) * 16;
  const float* sp = src + (size_t)(row0 + r) * ld + col0 + sc_;
#pragma unroll
  for (int g = 0; g < 4; ++g) {
    float4 v = *(const float4*)(sp + g * 4);
    unsigned pk = pack4(qtern(v.x, winv), qtern(v.y, winv),
                        qtern(v.z, winv), qtern(v.w, winv));
    *(unsigned*)(tile + r * 68 + sc_ + g * 4) = pk;
  }
  __syncthreads();
  int c = threadIdx.x >> 2, sr = (threadIdx.x & 3) * 16;
  unsigned o[4];
#pragma unroll
  for (int g = 0; g < 4; ++g) {
    int j = sr + g * 4;
    o[g] = pack4(tile[(j + 0) * 68 + c], tile[(j + 1) * 68 + c],
                 tile[(j + 2) * 68 + c], tile[(j + 3) * 68 + c]);
  }
  int4 ov = make_int4((int)o[0], (int)o[1], (int)o[2], (int)o[3]);
  *(int4*)(dst + (size_t)(col0 + c) * ldo + row0 + sr) = ov;
}

// ------------- GEMM1 (compact rows, gathered A): abuf_c = silu f32 + rowmax ----------
// fixed grid (16, CHTILES); XCD swizzle; tile j = tile0 + swizzled y
__global__ __launch_bounds__(256) void k_g1(
    const signed char* __restrict__ qh, const signed char* __restrict__ q1T,
    const int* __restrict__ rowexp, const int* __restrict__ tokidx,
    const float* __restrict__ srow1c, const int* __restrict__ meta, int tile0,
    float* __restrict__ abuf_c, unsigned* __restrict__ rowmaxc) {
  __shared__ __align__(16) signed char As[8192];
  __shared__ __align__(16) signed char Bs[8192];
  int lid = blockIdx.x + 16 * blockIdx.y;        // 0..575
  int nid = (lid & 7) * 72 + (lid >> 3);         // bijective XCD chunks
  int j = tile0 + (nid >> 4);
  if (j >= meta[0]) return;
  int colt = nid & 15;
  int col0 = colt * 128;
  int ei = rowexp[j];
  int tid = threadIdx.x, lane = tid & 63, wid = tid >> 6;
  int wr = wid >> 1, wc = wid & 1;
  int rowt0 = j * 128;
  // per-thread gathered A source pointers (k-invariant)
  int w_ = tid >> 6, l = tid & 63;
  int sub = l >> 2, seg = (l & 3) * 16;
  int sr0 = w_ * 32 + sub, sr1 = sr0 + 16;
  const signed char* a0 = qh + (size_t)tokidx[rowt0 + sr0] * DD + seg;
  const signed char* a1 = qh + (size_t)tokidx[rowt0 + sr1] * DD + seg;
  const signed char* b_src = q1T + (size_t)ei * FF * DD + (size_t)col0 * DD;
  signed char* lda0 = As + (w_ * 32) * 64;
  signed char* lda1 = As + (w_ * 32 + 16) * 64;
  int kg = (lane >> 4) * 16, rsel = lane & 15;
  v4i zero = {0, 0, 0, 0};
  v4i acc[4][4];
#pragma unroll
  for (int i = 0; i < 4; ++i)
#pragma unroll
    for (int jj = 0; jj < 4; ++jj) acc[i][jj] = zero;
  for (int k0 = 0; k0 < DD; k0 += 64) {
    __syncthreads();
    gll16(a0 + k0, lda0);
    gll16(a1 + k0, lda1);
    stage_rows<128>(b_src + k0, DD, Bs, tid);
    __syncthreads();
    v4i af[4], bf[4];
#pragma unroll
    for (int mi = 0; mi < 4; ++mi)
      af[mi] = *(const v4i*)(As + (wr * 64 + mi * 16 + rsel) * 64 + kg);
#pragma unroll
    for (int ni = 0; ni < 4; ++ni)
      bf[ni] = *(const v4i*)(Bs + (wc * 64 + ni * 16 + rsel) * 64 + kg);
#pragma unroll
    for (int mi = 0; mi < 4; ++mi)
#pragma unroll
      for (int ni = 0; ni < 4; ++ni)
        acc[mi][ni] = __builtin_amdgcn_mfma_i32_16x16x64_i8(af[mi], bf[ni], acc[mi][ni], 0, 0, 0);
  }
  int rlocal0 = (j - tile0) * 128;
#pragma unroll
  for (int mi = 0; mi < 4; ++mi) {
#pragma unroll
    for (int rg = 0; rg < 4; ++rg) {
      int tr = rowt0 + wr * 64 + mi * 16 + ((lane >> 4) << 2) + rg;
      float sA = srow1c[tr];
      float mloc = 0.f;
      int rl = rlocal0 + wr * 64 + mi * 16 + ((lane >> 4) << 2) + rg;
#pragma unroll
      for (int ni = 0; ni < 4; ++ni) {
        int fc = col0 + wc * 64 + ni * 16 + (lane & 15);
        float a = (float)acc[mi][ni][rg] * sA;
        float v = a / (1.f + expf(-a));
        abuf_c[(size_t)rl * FF + fc] = v;
        mloc = fmaxf(mloc, fabsf(v));
      }
#pragma unroll
      for (int o = 1; o < 16; o <<= 1) mloc = fmaxf(mloc, __shfl_xor(mloc, o));
      if ((lane & 15) == 0) atomicMax(rowmaxc + tr, __float_as_uint(mloc));
    }
  }
}

// ------------- aquant (chunk of compact rows) -------------
__global__ __launch_bounds__(256) void k_aq(
    const float* __restrict__ abuf_c, const unsigned* __restrict__ rowmaxc,
    const int* __restrict__ meta, int row0, signed char* __restrict__ qa) {
  int nrows = meta[1] - row0;
  if (nrows > CHROWS) nrows = CHROWS;
  int total4 = nrows * (FF / 4);
  int stride = gridDim.x * 256;
  for (int i = blockIdx.x * 256 + threadIdx.x; i < total4; i += stride) {
    int rl = i >> 9;
    int r = row0 + rl;
    float clip = fmaxf(__uint_as_float(rowmaxc[r]), 1e-5f);
    float s = 127.f / clip;
    float4 v = ((const float4*)abuf_c)[i];
    int q0 = (int)fminf(127.f, fmaxf(-128.f, rintf(v.x * s)));
    int q1 = (int)fminf(127.f, fmaxf(-128.f, rintf(v.y * s)));
    int q2 = (int)fminf(127.f, fmaxf(-128.f, rintf(v.z * s)));
    int q3 = (int)fminf(127.f, fmaxf(-128.f, rintf(v.w * s)));
    ((unsigned*)qa)[(size_t)r * (FF / 4) + (i & 511)] = pack4(q0, q1, q2, q3);
  }
}

// ------------- final gemm2 scale per compact row -------------
__global__ __launch_bounds__(256) void k_scg(
    const unsigned* __restrict__ rowmaxc, const double* __restrict__ wscale,
    const float* __restrict__ gates, const int* __restrict__ tokidx,
    const int* __restrict__ wrow, const int* __restrict__ rowexp,
    float* __restrict__ sgc) {
  int r = blockIdx.x * 256 + threadIdx.x;
  if (r >= NRMAX) return;
  int ei = rowexp[r >> 7];
  int w = wrow[r];
  if (ei < 0 || w < 0) { sgc[r] = 0.f; return; }
  float clip = fmaxf(__uint_as_float(rowmaxc[r]), 1e-5f);
  int t = tokidx[r];
  double csc = wscale[ei < 2 ? ei + 2 : ei + 10] * (1.0 / 127.0);
  float g = (ei < 2) ? 1.f : gates[(size_t)t * 8 + (ei - 2)];
  sgc[r] = (float)((double)clip * csc) * g;
}

// ------------- GEMM2 (compact rows): pbuf[plane][t] = scaled row -------------
// fixed grid (8, NTILEMAX); XCD swizzle (576 % 8 == 0)
__global__ __launch_bounds__(256) void k_g2(
    const signed char* __restrict__ qa, const signed char* __restrict__ q2T,
    const int* __restrict__ rowexp, const float* __restrict__ sgc,
    const int* __restrict__ wrow, const int* __restrict__ meta,
    float* __restrict__ pbuf) {
  __shared__ __align__(16) signed char As[8192];
  __shared__ __align__(16) signed char Bs[8192];
  int lid = blockIdx.x + 8 * blockIdx.y;        // 0..575
  int nid = (lid & 7) * 72 + (lid >> 3);
  int j = nid >> 3;
  if (j >= meta[0]) return;
  int col0 = (nid & 7) * 128;
  int ei = rowexp[j];
  int tid = threadIdx.x, lane = tid & 63, wid = tid >> 6;
  int wr = wid >> 1, wc = wid & 1;
  const signed char* ap = qa + (size_t)j * 128 * FF;
  const signed char* bp = q2T + (size_t)ei * DD * FF + (size_t)col0 * FF;
  int kg = (lane >> 4) * 16, rsel = lane & 15;
  v4i zero = {0, 0, 0, 0};
  v4i acc[4][4];
#pragma unroll
  for (int i = 0; i < 4; ++i)
#pragma unroll
    for (int jj = 0; jj < 4; ++jj) acc[i][jj] = zero;
  for (int k0 = 0; k0 < FF; k0 += 64) {
    __syncthreads();
    stage_rows<128>(ap + k0, FF, As, tid);
    stage_rows<128>(bp + k0, FF, Bs, tid);
    __syncthreads();
    v4i af[4], bf[4];
#pragma unroll
    for (int mi = 0; mi < 4; ++mi)
      af[mi] = *(const v4i*)(As + (wr * 64 + mi * 16 + rsel) * 64 + kg);
#pragma unroll
    for (int ni = 0; ni < 4; ++ni)
      bf[ni] = *(const v4i*)(Bs + (wc * 64 + ni * 16 + rsel) * 64 + kg);
#pragma unroll
    for (int mi = 0; mi < 4; ++mi)
#pragma unroll
      for (int ni = 0; ni < 4; ++ni)
        acc[mi][ni] = __builtin_amdgcn_mfma_i32_16x16x64_i8(af[mi], bf[ni], acc[mi][ni], 0, 0, 0);
  }
#pragma unroll
  for (int mi = 0; mi < 4; ++mi) {
#pragma unroll
    for (int rg = 0; rg < 4; ++rg) {
      int tr = j * 128 + wr * 64 + mi * 16 + ((lane >> 4) << 2) + rg;
      int w = wrow[tr];
      float sc = sgc[tr];
      if (w >= 0) {
#pragma unroll
        for (int ni = 0; ni < 4; ++ni) {
          int dc = col0 + wc * 64 + ni * 16 + (lane & 15);
          pbuf[(size_t)w * DD + dc] = (float)acc[mi][ni][rg] * sc;
        }
      }
    }
  }
}

// ------------- combine: out = sum of 4 planes -------------
__global__ __launch_bounds__(256) void k_combine(
    const float* __restrict__ pbuf, float* __restrict__ out) {
  int i = blockIdx.x * 256 + threadIdx.x;  // float4 index
  float4 s = ((const float4*)pbuf)[i];
#pragma unroll
  for (int z = 1; z < 4; ++z) {
    float4 v = ((const float4*)(pbuf + (size_t)z * TT * DD))[i];
    s.x += v.x; s.y += v.y; s.z += v.z; s.w += v.w;
  }
  ((float4*)out)[i] = s;
}

extern "C" void kernel_launch(void* const* d_in, const int* in_sizes, int n_in,
                              void* d_out, int out_size, void* d_ws, size_t ws_size,
                              hipStream_t stream) {
  const float* x    = (const float*)d_in[0];
  const float* rmsw = (const float*)d_in[1];
  const float* w1s  = (const float*)d_in[2];
  const float* w2s  = (const float*)d_in[3];
  const float* w1r  = (const float*)d_in[4];
  const float* w2r  = (const float*)d_in[5];
  const float* rw   = (const float*)d_in[6];
  float* out = (float*)d_out;

  char* ws = (char*)d_ws;
  // footprint ends at 0x7E80000 ~= 132.6MB (proven safe)
  double* amax_clip      = (double*)(ws + 0x0000000);   // 16KB
  double* part           = (double*)(ws + 0x0004000);   // 80KB
  double* wscale         = (double*)(ws + 0x0018000);   // 160B
  float* gates           = (float*)(ws + 0x0019000);    // 64KB
  int2* i01              = (int2*)(ws + 0x0029000);     // 16KB
  int* lists             = (int*)(ws + 0x002D000);      // 64KB
  unsigned char* slots   = (unsigned char*)(ws + 0x003D000); // 16KB
  int* cnt               = (int*)(ws + 0x0041000);      // 32B
  int* meta              = (int*)(ws + 0x0041100);      // 64B
  int* tokidx            = (int*)(ws + 0x0042000);      // 36KB
  int* wrow              = (int*)(ws + 0x004B000);      // 36KB
  float* srow1c          = (float*)(ws + 0x0054000);    // 36KB
  float* sgc             = (float*)(ws + 0x005D000);    // 36KB
  int* rowexp            = (int*)(ws + 0x0066000);      // 288B
  unsigned* rowmaxc      = (unsigned*)(ws + 0x0067000); // 36KB
  signed char* qh        = (signed char*)(ws + 0x0080000);    // 2MB
  __hip_bfloat16* hb     = (__hip_bfloat16*)(ws + 0x0280000); // 4MB
  signed char* q1T       = (signed char*)(ws + 0x0680000);    // 20MB
  signed char* q2T       = (signed char*)(ws + 0x1A80000);    // 20MB
  signed char* qa        = (signed char*)(ws + 0x2E80000);    // <=18.9MB (40MB region)
  float* pbuf            = (float*)(ws + 0x5680000);          // 4 planes = 32MB (40MB region)
  float* abuf_c          = pbuf;  // alias: chunk buffer (36.9MB) used before g2 writes pbuf

  k_zero<<<(NRMAX + 255) / 256, 256, 0, stream>>>(rowmaxc);
  k_rms_quant<<<TT, 256, 0, stream>>>(x, rmsw, qh, hb, amax_clip);
  k_wabs_part<<<20 * 512, 256, 0, stream>>>(w1s, w2s, w1r, w2r, part);
  k_wscale_final<<<20, 256, 0, stream>>>(part, wscale);
  k_router<<<TT, 64, 0, stream>>>(hb, rw, gates, i01);
  k_lists<<<8, 64, 0, stream>>>(i01, lists, slots, cnt);
  k_wquant<<<20 * 512, 256, 0, stream>>>(w1s, w2s, w1r, w2r, wscale, q1T, q2T);
  k_meta<<<1, 256, 0, stream>>>(cnt, lists, slots, amax_clip, wscale,
                                meta, rowexp, tokidx, wrow, srow1c);

  dim3 g1(16, CHTILES);
  k_g1<<<g1, 256, 0, stream>>>(qh, q1T, rowexp, tokidx, srow1c, meta, 0,
                               abuf_c, rowmaxc);
  k_aq<<<2048, 256, 0, stream>>>(abuf_c, rowmaxc, meta, 0, qa);
  k_g1<<<g1, 256, 0, stream>>>(qh, q1T, rowexp, tokidx, srow1c, meta, CHTILES,
                               abuf_c, rowmaxc);
  k_aq<<<2048, 256, 0, stream>>>(abuf_c, rowmaxc, meta, CHROWS, qa);

  k_scg<<<(NRMAX + 255) / 256, 256, 0, stream>>>(rowmaxc, wscale, gates,
                                                 tokidx, wrow, rowexp, sgc);
  dim3 g2(8, NTILEMAX);
  k_g2<<<g2, 256, 0, stream>>>(qa, q2T, rowexp, sgc, wrow, meta, pbuf);
  k_combine<<<TT * DD / 4 / 256, 256, 0, stream>>>(pbuf, out);
}

// Round 13
// 254.541 us; speedup vs baseline: 1.4362x; 1.0484x over previous
//
#include <hip/hip_runtime.h>
#include <hip/hip_bf16.h>

#define TT 2048
#define DD 1024
#define FF 2048
#define NEXPI 10     // 2 shared + 8 routed expert instances
#define NRMAX 9216   // max compact rows: 4096 shared + 4096 routed + <=1024 pad
#define NTILEMAX 72  // NRMAX/128
#define CHTILES 36   // row-tiles per gemm1 chunk
#define CHROWS (CHTILES * 128)

typedef __attribute__((ext_vector_type(4))) int v4i;

__device__ __forceinline__ double wave_sum_d(double v) {
#pragma unroll
  for (int o = 32; o > 0; o >>= 1) v += __shfl_down(v, o);
  return v;
}
__device__ __forceinline__ double wave_max_d(double v) {
#pragma unroll
  for (int o = 32; o > 0; o >>= 1) v = fmax(v, __shfl_down(v, o));
  return v;
}

// async global->LDS, 16B per lane; lds dest is wave-uniform base, lane l lands at +l*16
__device__ __forceinline__ void gll16(const void* g, void* l) {
  __builtin_amdgcn_global_load_lds(
      (const __attribute__((address_space(1))) void*)g,
      (__attribute__((address_space(3))) void*)l, 16, 0, 0);
}

// stage ROWS x 64B tile (i8, row stride K bytes in global) into linear LDS
template<int ROWS>
__device__ __forceinline__ void stage_rows(const signed char* src, int K,
                                           signed char* lds, int tid) {
  int w = tid >> 6, l = tid & 63;
  int sub = l >> 2, seg = (l & 3) * 16;
#pragma unroll
  for (int i = 0; i < ROWS / 64; ++i) {
    int rbase = w * (ROWS / 4) + i * 16;
    gll16(src + (size_t)(rbase + sub) * K + seg, lds + rbase * 64);
  }
}

// ---------------- zero init (compact rowmax) ----------------
__global__ void k_zero(unsigned* __restrict__ rm) {
  int i = blockIdx.x * 256 + threadIdx.x;
  if (i < NRMAX) rm[i] = 0u;
}

// ------------- rmsnorm + per-token absmax + int8 quant + bf16 h (f64 math) -------------
__global__ __launch_bounds__(256) void k_rms_quant(
    const float* __restrict__ x, const float* __restrict__ rw,
    signed char* __restrict__ qh, __hip_bfloat16* __restrict__ hb,
    double* __restrict__ amax_clip) {
  __shared__ double red[12];
  int t = blockIdx.x, tid = threadIdx.x;
  int lane = tid & 63, wid = tid >> 6;
  float4 xv = ((const float4*)(x + (size_t)t * DD))[tid];
  double x0 = xv.x, x1 = xv.y, x2 = xv.z, x3 = xv.w;
  double ss = x0 * x0 + x1 * x1 + x2 * x2 + x3 * x3;
  ss = wave_sum_d(ss);
  if (lane == 0) red[wid] = ss;
  __syncthreads();
  if (tid == 0) {
    double s = red[0] + red[1] + red[2] + red[3];
    red[8] = 1.0 / sqrt(s * (1.0 / DD) + 1e-6);
  }
  __syncthreads();
  double r = red[8];
  float4 wv = ((const float4*)rw)[tid];
  double h0 = x0 * r * (double)wv.x, h1 = x1 * r * (double)wv.y;
  double h2 = x2 * r * (double)wv.z, h3 = x3 * r * (double)wv.w;
  __hip_bfloat16* hp = hb + (size_t)t * DD + tid * 4;
  hp[0] = __float2bfloat16((float)h0); hp[1] = __float2bfloat16((float)h1);
  hp[2] = __float2bfloat16((float)h2); hp[3] = __float2bfloat16((float)h3);
  double am = fmax(fmax(fabs(h0), fabs(h1)), fmax(fabs(h2), fabs(h3)));
  am = wave_max_d(am);
  if (lane == 0) red[4 + wid] = am;
  __syncthreads();
  if (tid == 0) {
    double a = fmax(fmax(red[4], red[5]), fmax(red[6], red[7]));
    red[9] = fmax(a, 1e-5);
  }
  __syncthreads();
  double clipv = red[9];
  if (tid == 0) amax_clip[t] = clipv;
  double s = 127.0 / clipv;
  int q0 = (int)fmin(127.0, fmax(-128.0, rint(h0 * s)));
  int q1 = (int)fmin(127.0, fmax(-128.0, rint(h1 * s)));
  int q2 = (int)fmin(127.0, fmax(-128.0, rint(h2 * s)));
  int q3 = (int)fmin(127.0, fmax(-128.0, rint(h3 * s)));
  unsigned pw = (unsigned)(q0 & 255) | ((unsigned)(q1 & 255) << 8) |
                ((unsigned)(q2 & 255) << 16) | ((unsigned)(q3 & 255) << 24);
  *(unsigned*)(qh + (size_t)t * DD + tid * 4) = pw;
}

// ------------- weight absmean: f64 partial sums, 20 matrices x 512 blocks -------------
__global__ __launch_bounds__(256) void k_wabs_part(
    const float* __restrict__ w1s, const float* __restrict__ w2s,
    const float* __restrict__ w1r, const float* __restrict__ w2r,
    double* __restrict__ part) {
  __shared__ double red[4];
  int m = blockIdx.x >> 9, blk = blockIdx.x & 511;
  const float* base;
  if (m < 2)       base = w1s + (size_t)m * (DD * FF);
  else if (m < 4)  base = w2s + (size_t)(m - 2) * (DD * FF);
  else if (m < 12) base = w1r + (size_t)(m - 4) * (DD * FF);
  else             base = w2r + (size_t)(m - 12) * (DD * FF);
  const float4* p = (const float4*)(base + (size_t)blk * 4096);
  int tid = threadIdx.x;
  float4 va = p[tid];
  float4 vb = p[tid + 256];
  float4 vc = p[tid + 512];
  float4 vd = p[tid + 768];
  double s0 = (double)fabsf(va.x) + (double)fabsf(va.y) + (double)fabsf(va.z) + (double)fabsf(va.w);
  double s1 = (double)fabsf(vb.x) + (double)fabsf(vb.y) + (double)fabsf(vb.z) + (double)fabsf(vb.w);
  double s2 = (double)fabsf(vc.x) + (double)fabsf(vc.y) + (double)fabsf(vc.z) + (double)fabsf(vc.w);
  double s3 = (double)fabsf(vd.x) + (double)fabsf(vd.y) + (double)fabsf(vd.z) + (double)fabsf(vd.w);
  double s = (s0 + s1) + (s2 + s3);
  s = wave_sum_d(s);
  int lane = tid & 63, wid = tid >> 6;
  if (lane == 0) red[wid] = s;
  __syncthreads();
  if (tid == 0) part[m * 512 + blk] = red[0] + red[1] + red[2] + red[3];
}

__global__ __launch_bounds__(256) void k_wscale_final(
    const double* __restrict__ part, double* __restrict__ wscale) {
  __shared__ double red[4];
  int m = blockIdx.x, tid = threadIdx.x;
  double v = part[m * 512 + tid] + part[m * 512 + 256 + tid];
  v = wave_sum_d(v);
  if ((tid & 63) == 0) red[tid >> 6] = v;
  __syncthreads();
  if (tid == 0)
    wscale[m] = (red[0] + red[1] + red[2] + red[3]) * (1.0 / 2097152.0) + 1e-8;
}

// ------------- router: bf16 products, f64 accum, bf16-rounded logits,
//               top-2 (lower-index tie-break), renorm -> dense gates + (i0,i1) ---------
__global__ __launch_bounds__(64) void k_router(
    const __hip_bfloat16* __restrict__ hb, const float* __restrict__ rw,
    float* __restrict__ gates, int2* __restrict__ i01) {
  int t = blockIdx.x, lane = threadIdx.x;
  double acc[8];
#pragma unroll
  for (int e = 0; e < 8; ++e) acc[e] = 0.0;
  const __hip_bfloat16* hp = hb + (size_t)t * DD;
  for (int d = lane; d < DD; d += 64) {
    double hv = (double)__bfloat162float(hp[d]);
#pragma unroll
    for (int e = 0; e < 8; ++e) {
      double wv = (double)__bfloat162float(__float2bfloat16(rw[e * DD + d]));
      acc[e] += hv * wv;
    }
  }
#pragma unroll
  for (int e = 0; e < 8; ++e) acc[e] = wave_sum_d(acc[e]);
  if (lane == 0) {
    double lb[8];
#pragma unroll
    for (int e = 0; e < 8; ++e)
      lb[e] = (double)__bfloat162float(__float2bfloat16((float)acc[e]));
    double mx = lb[0];
#pragma unroll
    for (int e = 1; e < 8; ++e) mx = fmax(mx, lb[e]);
    double p[8];
#pragma unroll
    for (int e = 0; e < 8; ++e) p[e] = exp(lb[e] - mx);
    int i0 = 0;
    for (int e = 1; e < 8; ++e) if (p[e] > p[i0]) i0 = e;
    int i1 = (i0 == 0) ? 1 : 0;
    for (int e = 0; e < 8; ++e) if (e != i0 && p[e] > p[i1]) i1 = e;
    double den = p[i0] + p[i1];
    float o[8] = {0.f, 0.f, 0.f, 0.f, 0.f, 0.f, 0.f, 0.f};
    o[i0] = (float)(p[i0] / den);
    o[i1] = (float)(p[i1] / den);
#pragma unroll
    for (int e = 0; e < 8; ++e) gates[(size_t)t * 8 + e] = o[e];
    i01[t] = make_int2(i0, i1);
  }
}

// ------------- per-expert ordered token lists (ballot prefix compaction) ---------------
__global__ __launch_bounds__(64) void k_lists(
    const int2* __restrict__ i01, int* __restrict__ lists,
    unsigned char* __restrict__ slots, int* __restrict__ cnt) {
  int e = blockIdx.x, lane = threadIdx.x;
  int* le = lists + e * TT;
  unsigned char* se = slots + e * TT;
  int base = 0;
  for (int it = 0; it < TT / 64; ++it) {
    int t = it * 64 + lane;
    int2 r = i01[t];
    bool hit0 = (r.x == e), hit1 = (r.y == e);
    bool hit = hit0 || hit1;
    unsigned long long m = __ballot(hit);
    int pos = base + __popcll(m & ((1ull << lane) - 1ull));
    if (hit) { le[pos] = t; se[pos] = hit0 ? 0 : 1; }
    base += __popcll(m);
  }
  if (lane == 0) cnt[e] = base;
}

// ------------- meta: segment offsets, tile->expert map, per-row gather tables ----------
__global__ __launch_bounds__(256) void k_meta(
    const int* __restrict__ cnt, const int* __restrict__ lists,
    const unsigned char* __restrict__ slots, const double* __restrict__ amax_clip,
    const double* __restrict__ wscale, int* __restrict__ meta,
    int* __restrict__ rowexp, int* __restrict__ tokidx,
    int* __restrict__ wrow, float* __restrict__ srow1c) {
  __shared__ int segs[9];
  __shared__ int scnt[8];
  int tid = threadIdx.x;
  if (tid == 0) {
    int acc = 0;
    for (int e = 0; e < 8; ++e) {
      scnt[e] = cnt[e];
      segs[e] = acc;
      acc += (cnt[e] + 127) & ~127;
    }
    segs[8] = acc;
    meta[0] = 32 + acc / 128;   // total row-tiles
    meta[1] = 4096 + acc;       // total compact rows
  }
  __syncthreads();
  int ntile = 32 + segs[8] / 128;
  for (int j = tid; j < NTILEMAX; j += 256) {
    int ei = -1;
    if (j < 16) ei = 0;
    else if (j < 32) ei = 1;
    else if (j < ntile) {
      int rr = (j - 32) * 128;
      for (int e = 0; e < 8; ++e)
        if (rr >= segs[e] && rr < segs[e + 1]) { ei = 2 + e; break; }
    }
    rowexp[j] = ei;
  }
  for (int r = tid; r < NRMAX; r += 256) {
    int t = 0; float s1 = 0.f; int w = -1;
    if (r < 4096) {
      int e = r >> 11; t = r & (TT - 1);
      double csc = wscale[e] * (1.0 / 127.0);
      s1 = (float)(amax_clip[t] * csc);
      w = e * TT + t;
    } else {
      int rr = r - 4096;
      if (rr < segs[8]) {
        int e = 0;
        for (int q = 0; q < 8; ++q)
          if (rr >= segs[q] && rr < segs[q + 1]) { e = q; break; }
        int k = rr - segs[e];
        if (k < scnt[e]) {
          t = lists[e * TT + k];
          int sl = slots[e * TT + k];
          double csc = wscale[4 + e] * (1.0 / 127.0);
          s1 = (float)(amax_clip[t] * csc);
          w = (2 + sl) * TT + t;
        }
      }
    }
    tokidx[r] = t; srow1c[r] = s1; wrow[r] = w;
  }
}

// ------------- ternary quant helper (f64 bins) -------------
__device__ __forceinline__ int qtern(float v, double winv) {
  double q = rint((double)v * winv);
  return (int)fmin(1.0, fmax(-1.0, q));
}
__device__ __forceinline__ unsigned pack4(int a, int b, int c, int d) {
  return (unsigned)(a & 255) | ((unsigned)(b & 255) << 8) |
         ((unsigned)(c & 255) << 16) | ((unsigned)(d & 255) << 24);
}

// ------------- weight quant + transpose: f32 [R][C] -> i8 W^T [C][R] -------------
__global__ __launch_bounds__(256) void k_wquant(
    const float* __restrict__ w1s, const float* __restrict__ w2s,
    const float* __restrict__ w1r, const float* __restrict__ w2r,
    const double* __restrict__ wscale,
    signed char* __restrict__ q1T, signed char* __restrict__ q2T) {
  __shared__ signed char tile[64 * 68];
  int bid = blockIdx.x;
  int m = bid >> 9, t = bid & 511;
  const float* src;
  signed char* dst;
  int ld, ldo, rt, ct;
  if (m < 2) {
    src = w1s + (size_t)m * DD * FF;
    dst = q1T + (size_t)m * FF * DD;
    ld = FF; ldo = DD; rt = t >> 5; ct = t & 31;
  } else if (m < 4) {
    src = w2s + (size_t)(m - 2) * FF * DD;
    dst = q2T + (size_t)(m - 2) * DD * FF;
    ld = DD; ldo = FF; rt = t >> 4; ct = t & 15;
  } else if (m < 12) {
    src = w1r + (size_t)(m - 4) * DD * FF;
    dst = q1T + (size_t)(m - 2) * FF * DD;
    ld = FF; ldo = DD; rt = t >> 5; ct = t & 31;
  } else {
    src = w2r + (size_t)(m - 12) * FF * DD;
    dst = q2T + (size_t)(m - 10) * DD * FF;
    ld = DD; ldo = FF; rt = t >> 4; ct = t & 15;
  }
  double winv = 1.0 / wscale[m];
  int row0 = rt * 64, col0 = ct * 64;
  int r = threadIdx.x >> 2, sc_ = (threadIdx.x & 3) * 16;
  const float* sp = src + (size_t)(row0 + r) * ld + col0 + sc_;
#pragma unroll
  for (int g = 0; g < 4; ++g) {
    float4 v = *(const float4*)(sp + g * 4);
    unsigned pk = pack4(qtern(v.x, winv), qtern(v.y, winv),
                        qtern(v.z, winv), qtern(v.w, winv));
    *(unsigned*)(tile + r * 68 + sc_ + g * 4) = pk;
  }
  __syncthreads();
  int c = threadIdx.x >> 2, sr = (threadIdx.x & 3) * 16;
  unsigned o[4];
#pragma unroll
  for (int g = 0; g < 4; ++g) {
    int j = sr + g * 4;
    o[g] = pack4(tile[(j + 0) * 68 + c], tile[(j + 1) * 68 + c],
                 tile[(j + 2) * 68 + c], tile[(j + 3) * 68 + c]);
  }
  int4 ov = make_int4((int)o[0], (int)o[1], (int)o[2], (int)o[3]);
  *(int4*)(dst + (size_t)(col0 + c) * ldo + row0 + sr) = ov;
}

// ------------- GEMM1 (compact rows, gathered A): 128x64 tiles -----------------------
// fixed grid (32, CHTILES) = 1152 blocks; bijective XCD swizzle (chunks of 144)
__global__ __launch_bounds__(256) void k_g1(
    const signed char* __restrict__ qh, const signed char* __restrict__ q1T,
    const int* __restrict__ rowexp, const int* __restrict__ tokidx,
    const float* __restrict__ srow1c, const int* __restrict__ meta, int tile0,
    float* __restrict__ abuf_c, unsigned* __restrict__ rowmaxc) {
  __shared__ __align__(16) signed char As[8192];   // 128 rows x 64 B
  __shared__ __align__(16) signed char Bs[4096];   // 64 rows x 64 B
  int lid = blockIdx.x + 32 * blockIdx.y;          // 0..1151
  int nid = (lid & 7) * 144 + (lid >> 3);          // bijective XCD chunks
  int j = tile0 + (nid >> 5);
  if (j >= meta[0]) return;
  int col0 = (nid & 31) * 64;
  int ei = rowexp[j];
  int tid = threadIdx.x, lane = tid & 63, wid = tid >> 6;
  int wr = wid >> 1, wc = wid & 1;
  int rowt0 = j * 128;
  // per-thread gathered A source pointers (k-invariant)
  int sub = lane >> 2, seg = (lane & 3) * 16;
  int sr0 = wid * 32 + sub, sr1 = sr0 + 16;
  const signed char* a0 = qh + (size_t)tokidx[rowt0 + sr0] * DD + seg;
  const signed char* a1 = qh + (size_t)tokidx[rowt0 + sr1] * DD + seg;
  const signed char* b_src = q1T + (size_t)ei * FF * DD + (size_t)col0 * DD;
  signed char* lda0 = As + (wid * 32) * 64;
  signed char* lda1 = As + (wid * 32 + 16) * 64;
  int kg = (lane >> 4) * 16, rsel = lane & 15;
  v4i zero = {0, 0, 0, 0};
  v4i acc[4][2];
#pragma unroll
  for (int i = 0; i < 4; ++i)
#pragma unroll
    for (int jj = 0; jj < 2; ++jj) acc[i][jj] = zero;
  for (int k0 = 0; k0 < DD; k0 += 64) {
    __syncthreads();
    gll16(a0 + k0, lda0);
    gll16(a1 + k0, lda1);
    stage_rows<64>(b_src + k0, DD, Bs, tid);
    __syncthreads();
    v4i af[4], bf[2];
#pragma unroll
    for (int mi = 0; mi < 4; ++mi)
      af[mi] = *(const v4i*)(As + (wr * 64 + mi * 16 + rsel) * 64 + kg);
#pragma unroll
    for (int ni = 0; ni < 2; ++ni)
      bf[ni] = *(const v4i*)(Bs + (wc * 32 + ni * 16 + rsel) * 64 + kg);
#pragma unroll
    for (int mi = 0; mi < 4; ++mi)
#pragma unroll
      for (int ni = 0; ni < 2; ++ni)
        acc[mi][ni] = __builtin_amdgcn_mfma_i32_16x16x64_i8(af[mi], bf[ni], acc[mi][ni], 0, 0, 0);
  }
  int rlocal0 = (j - tile0) * 128;
#pragma unroll
  for (int mi = 0; mi < 4; ++mi) {
#pragma unroll
    for (int rg = 0; rg < 4; ++rg) {
      int rof = wr * 64 + mi * 16 + ((lane >> 4) << 2) + rg;
      int tr = rowt0 + rof;
      float sA = srow1c[tr];
      float mloc = 0.f;
      int rl = rlocal0 + rof;
#pragma unroll
      for (int ni = 0; ni < 2; ++ni) {
        int fc = col0 + wc * 32 + ni * 16 + (lane & 15);
        float a = (float)acc[mi][ni][rg] * sA;
        float v = a / (1.f + expf(-a));
        abuf_c[(size_t)rl * FF + fc] = v;
        mloc = fmaxf(mloc, fabsf(v));
      }
#pragma unroll
      for (int o = 1; o < 16; o <<= 1) mloc = fmaxf(mloc, __shfl_xor(mloc, o));
      if ((lane & 15) == 0) atomicMax(rowmaxc + tr, __float_as_uint(mloc));
    }
  }
}

// ------------- aquant (chunk of compact rows) -------------
__global__ __launch_bounds__(256) void k_aq(
    const float* __restrict__ abuf_c, const unsigned* __restrict__ rowmaxc,
    const int* __restrict__ meta, int row0, signed char* __restrict__ qa) {
  int nrows = meta[1] - row0;
  if (nrows > CHROWS) nrows = CHROWS;
  if (nrows < 0) nrows = 0;
  int total4 = nrows * (FF / 4);
  int stride = gridDim.x * 256;
  for (int i = blockIdx.x * 256 + threadIdx.x; i < total4; i += stride) {
    int rl = i >> 9;
    int r = row0 + rl;
    float clip = fmaxf(__uint_as_float(rowmaxc[r]), 1e-5f);
    float s = 127.f / clip;
    float4 v = ((const float4*)abuf_c)[i];
    int q0 = (int)fminf(127.f, fmaxf(-128.f, rintf(v.x * s)));
    int q1 = (int)fminf(127.f, fmaxf(-128.f, rintf(v.y * s)));
    int q2 = (int)fminf(127.f, fmaxf(-128.f, rintf(v.z * s)));
    int q3 = (int)fminf(127.f, fmaxf(-128.f, rintf(v.w * s)));
    ((unsigned*)qa)[(size_t)r * (FF / 4) + (i & 511)] = pack4(q0, q1, q2, q3);
  }
}

// ------------- final gemm2 scale per compact row -------------
__global__ __launch_bounds__(256) void k_scg(
    const unsigned* __restrict__ rowmaxc, const double* __restrict__ wscale,
    const float* __restrict__ gates, const int* __restrict__ tokidx,
    const int* __restrict__ wrow, const int* __restrict__ rowexp,
    float* __restrict__ sgc) {
  int r = blockIdx.x * 256 + threadIdx.x;
  if (r >= NRMAX) return;
  int ei = rowexp[r >> 7];
  int w = wrow[r];
  if (ei < 0 || w < 0) { sgc[r] = 0.f; return; }
  float clip = fmaxf(__uint_as_float(rowmaxc[r]), 1e-5f);
  int t = tokidx[r];
  double csc = wscale[ei < 2 ? ei + 2 : ei + 10] * (1.0 / 127.0);
  float g = (ei < 2) ? 1.f : gates[(size_t)t * 8 + (ei - 2)];
  sgc[r] = (float)((double)clip * csc) * g;
}

// ------------- GEMM2 (compact rows): 128x64 tiles; pbuf[plane][t] = scaled row ------
// fixed grid (16, NTILEMAX) = 1152 blocks; bijective XCD swizzle (chunks of 144)
__global__ __launch_bounds__(256) void k_g2(
    const signed char* __restrict__ qa, const signed char* __restrict__ q2T,
    const int* __restrict__ rowexp, const float* __restrict__ sgc,
    const int* __restrict__ wrow, const int* __restrict__ meta,
    float* __restrict__ pbuf) {
  __shared__ __align__(16) signed char As[8192];   // 128 rows x 64 B
  __shared__ __align__(16) signed char Bs[4096];   // 64 rows x 64 B
  int lid = blockIdx.x + 16 * blockIdx.y;          // 0..1151
  int nid = (lid & 7) * 144 + (lid >> 3);
  int j = nid >> 4;
  if (j >= meta[0]) return;
  int col0 = (nid & 15) * 64;
  int ei = rowexp[j];
  int tid = threadIdx.x, lane = tid & 63, wid = tid >> 6;
  int wr = wid >> 1, wc = wid & 1;
  const signed char* ap = qa + (size_t)j * 128 * FF;
  const signed char* bp = q2T + (size_t)ei * DD * FF + (size_t)col0 * FF;
  int kg = (lane >> 4) * 16, rsel = lane & 15;
  v4i zero = {0, 0, 0, 0};
  v4i acc[4][2];
#pragma unroll
  for (int i = 0; i < 4; ++i)
#pragma unroll
    for (int jj = 0; jj < 2; ++jj) acc[i][jj] = zero;
  for (int k0 = 0; k0 < FF; k0 += 64) {
    __syncthreads();
    stage_rows<128>(ap + k0, FF, As, tid);
    stage_rows<64>(bp + k0, FF, Bs, tid);
    __syncthreads();
    v4i af[4], bf[2];
#pragma unroll
    for (int mi = 0; mi < 4; ++mi)
      af[mi] = *(const v4i*)(As + (wr * 64 + mi * 16 + rsel) * 64 + kg);
#pragma unroll
    for (int ni = 0; ni < 2; ++ni)
      bf[ni] = *(const v4i*)(Bs + (wc * 32 + ni * 16 + rsel) * 64 + kg);
#pragma unroll
    for (int mi = 0; mi < 4; ++mi)
#pragma unroll
      for (int ni = 0; ni < 2; ++ni)
        acc[mi][ni] = __builtin_amdgcn_mfma_i32_16x16x64_i8(af[mi], bf[ni], acc[mi][ni], 0, 0, 0);
  }
#pragma unroll
  for (int mi = 0; mi < 4; ++mi) {
#pragma unroll
    for (int rg = 0; rg < 4; ++rg) {
      int tr = j * 128 + wr * 64 + mi * 16 + ((lane >> 4) << 2) + rg;
      int w = wrow[tr];
      float sc = sgc[tr];
      if (w >= 0) {
#pragma unroll
        for (int ni = 0; ni < 2; ++ni) {
          int dc = col0 + wc * 32 + ni * 16 + (lane & 15);
          pbuf[(size_t)w * DD + dc] = (float)acc[mi][ni][rg] * sc;
        }
      }
    }
  }
}

// ------------- combine: out = sum of 4 planes -------------
__global__ __launch_bounds__(256) void k_combine(
    const float* __restrict__ pbuf, float* __restrict__ out) {
  int i = blockIdx.x * 256 + threadIdx.x;  // float4 index
  float4 s = ((const float4*)pbuf)[i];
#pragma unroll
  for (int z = 1; z < 4; ++z) {
    float4 v = ((const float4*)(pbuf + (size_t)z * TT * DD))[i];
    s.x += v.x; s.y += v.y; s.z += v.z; s.w += v.w;
  }
  ((float4*)out)[i] = s;
}

extern "C" void kernel_launch(void* const* d_in, const int* in_sizes, int n_in,
                              void* d_out, int out_size, void* d_ws, size_t ws_size,
                              hipStream_t stream) {
  const float* x    = (const float*)d_in[0];
  const float* rmsw = (const float*)d_in[1];
  const float* w1s  = (const float*)d_in[2];
  const float* w2s  = (const float*)d_in[3];
  const float* w1r  = (const float*)d_in[4];
  const float* w2r  = (const float*)d_in[5];
  const float* rw   = (const float*)d_in[6];
  float* out = (float*)d_out;

  char* ws = (char*)d_ws;
  // footprint ends at 0x7E80000 ~= 132.6MB (proven safe)
  double* amax_clip      = (double*)(ws + 0x0000000);   // 16KB
  double* part           = (double*)(ws + 0x0004000);   // 80KB
  double* wscale         = (double*)(ws + 0x0018000);   // 160B
  float* gates           = (float*)(ws + 0x0019000);    // 64KB
  int2* i01              = (int2*)(ws + 0x0029000);     // 16KB
  int* lists             = (int*)(ws + 0x002D000);      // 64KB
  unsigned char* slots   = (unsigned char*)(ws + 0x003D000); // 16KB
  int* cnt               = (int*)(ws + 0x0041000);      // 32B
  int* meta              = (int*)(ws + 0x0041100);      // 64B
  int* tokidx            = (int*)(ws + 0x0042000);      // 36KB
  int* wrow              = (int*)(ws + 0x004B000);      // 36KB
  float* srow1c          = (float*)(ws + 0x0054000);    // 36KB
  float* sgc             = (float*)(ws + 0x005D000);    // 36KB
  int* rowexp            = (int*)(ws + 0x0066000);      // 288B
  unsigned* rowmaxc      = (unsigned*)(ws + 0x0067000); // 36KB
  signed char* qh        = (signed char*)(ws + 0x0080000);    // 2MB
  __hip_bfloat16* hb     = (__hip_bfloat16*)(ws + 0x0280000); // 4MB
  signed char* q1T       = (signed char*)(ws + 0x0680000);    // 20MB
  signed char* q2T       = (signed char*)(ws + 0x1A80000);    // 20MB
  signed char* qa        = (signed char*)(ws + 0x2E80000);    // <=18.9MB (40MB region)
  float* pbuf            = (float*)(ws + 0x5680000);          // 4 planes = 32MB (40MB region)
  float* abuf_c          = pbuf;  // alias: chunk buffer (36.9MB) used before g2 writes pbuf

  k_zero<<<(NRMAX + 255) / 256, 256, 0, stream>>>(rowmaxc);
  k_rms_quant<<<TT, 256, 0, stream>>>(x, rmsw, qh, hb, amax_clip);
  k_wabs_part<<<20 * 512, 256, 0, stream>>>(w1s, w2s, w1r, w2r, part);
  k_wscale_final<<<20, 256, 0, stream>>>(part, wscale);
  k_router<<<TT, 64, 0, stream>>>(hb, rw, gates, i01);
  k_lists<<<8, 64, 0, stream>>>(i01, lists, slots, cnt);
  k_wquant<<<20 * 512, 256, 0, stream>>>(w1s, w2s, w1r, w2r, wscale, q1T, q2T);
  k_meta<<<1, 256, 0, stream>>>(cnt, lists, slots, amax_clip, wscale,
                                meta, rowexp, tokidx, wrow, srow1c);

  dim3 g1(32, CHTILES);
  k_g1<<<g1, 256, 0, stream>>>(qh, q1T, rowexp, tokidx, srow1c, meta, 0,
                               abuf_c, rowmaxc);
  k_aq<<<2048, 256, 0, stream>>>(abuf_c, rowmaxc, meta, 0, qa);
  k_g1<<<g1, 256, 0, stream>>>(qh, q1T, rowexp, tokidx, srow1c, meta, CHTILES,
                               abuf_c, rowmaxc);
  k_aq<<<2048, 256, 0, stream>>>(abuf_c, rowmaxc, meta, CHROWS, qa);

  k_scg<<<(NRMAX + 255) / 256, 256, 0, stream>>>(rowmaxc, wscale, gates,
                                                 tokidx, wrow, rowexp, sgc);
  dim3 g2(16, NTILEMAX);
  k_g2<<<g2, 256, 0, stream>>>(qa, q2T, rowexp, sgc, wrow, meta, pbuf);
  k_combine<<<TT * DD / 4 / 256, 256, 0, stream>>>(pbuf, out);
}

// Round 14
// 254.539 us; speedup vs baseline: 1.4362x; 1.0000x over previous
//
#include <hip/hip_runtime.h>
#include <hip/hip_bf16.h>

#define TT 2048
#define DD 1024
#define FF 2048
#define NEXPI 10     // 2 shared + 8 routed expert instances
#define NRMAX 9216   // max compact rows: 4096 shared + 4096 routed + <=1024 pad
#define NTILEMAX 72  // NRMAX/128
#define CHTILES 36   // row-tiles per gemm1 chunk
#define CHROWS (CHTILES * 128)

typedef __attribute__((ext_vector_type(4))) int v4i;

__device__ __forceinline__ double wave_sum_d(double v) {
#pragma unroll
  for (int o = 32; o > 0; o >>= 1) v += __shfl_down(v, o);
  return v;
}
__device__ __forceinline__ double wave_max_d(double v) {
#pragma unroll
  for (int o = 32; o > 0; o >>= 1) v = fmax(v, __shfl_down(v, o));
  return v;
}

// async global->LDS, 16B per lane; lds dest is wave-uniform base, lane l lands at +l*16
__device__ __forceinline__ void gll16(const void* g, void* l) {
  __builtin_amdgcn_global_load_lds(
      (const __attribute__((address_space(1))) void*)g,
      (__attribute__((address_space(3))) void*)l, 16, 0, 0);
}

// stage ROWS x 64B tile (i8, row stride K bytes in global) into linear LDS
template<int ROWS>
__device__ __forceinline__ void stage_rows(const signed char* src, int K,
                                           signed char* lds, int tid) {
  int w = tid >> 6, l = tid & 63;
  int sub = l >> 2, seg = (l & 3) * 16;
#pragma unroll
  for (int i = 0; i < ROWS / 64; ++i) {
    int rbase = w * (ROWS / 4) + i * 16;
    gll16(src + (size_t)(rbase + sub) * K + seg, lds + rbase * 64);
  }
}

// ---------------- zero init (compact rowmax) ----------------
__global__ void k_zero(unsigned* __restrict__ rm) {
  int i = blockIdx.x * 256 + threadIdx.x;
  if (i < NRMAX) rm[i] = 0u;
}

// ------------- rmsnorm + per-token absmax + int8 quant + bf16 h (f64 math) -------------
__global__ __launch_bounds__(256) void k_rms_quant(
    const float* __restrict__ x, const float* __restrict__ rw,
    signed char* __restrict__ qh, __hip_bfloat16* __restrict__ hb,
    double* __restrict__ amax_clip) {
  __shared__ double red[12];
  int t = blockIdx.x, tid = threadIdx.x;
  int lane = tid & 63, wid = tid >> 6;
  float4 xv = ((const float4*)(x + (size_t)t * DD))[tid];
  double x0 = xv.x, x1 = xv.y, x2 = xv.z, x3 = xv.w;
  double ss = x0 * x0 + x1 * x1 + x2 * x2 + x3 * x3;
  ss = wave_sum_d(ss);
  if (lane == 0) red[wid] = ss;
  __syncthreads();
  if (tid == 0) {
    double s = red[0] + red[1] + red[2] + red[3];
    red[8] = 1.0 / sqrt(s * (1.0 / DD) + 1e-6);
  }
  __syncthreads();
  double r = red[8];
  float4 wv = ((const float4*)rw)[tid];
  double h0 = x0 * r * (double)wv.x, h1 = x1 * r * (double)wv.y;
  double h2 = x2 * r * (double)wv.z, h3 = x3 * r * (double)wv.w;
  __hip_bfloat16* hp = hb + (size_t)t * DD + tid * 4;
  hp[0] = __float2bfloat16((float)h0); hp[1] = __float2bfloat16((float)h1);
  hp[2] = __float2bfloat16((float)h2); hp[3] = __float2bfloat16((float)h3);
  double am = fmax(fmax(fabs(h0), fabs(h1)), fmax(fabs(h2), fabs(h3)));
  am = wave_max_d(am);
  if (lane == 0) red[4 + wid] = am;
  __syncthreads();
  if (tid == 0) {
    double a = fmax(fmax(red[4], red[5]), fmax(red[6], red[7]));
    red[9] = fmax(a, 1e-5);
  }
  __syncthreads();
  double clipv = red[9];
  if (tid == 0) amax_clip[t] = clipv;
  double s = 127.0 / clipv;
  int q0 = (int)fmin(127.0, fmax(-128.0, rint(h0 * s)));
  int q1 = (int)fmin(127.0, fmax(-128.0, rint(h1 * s)));
  int q2 = (int)fmin(127.0, fmax(-128.0, rint(h2 * s)));
  int q3 = (int)fmin(127.0, fmax(-128.0, rint(h3 * s)));
  unsigned pw = (unsigned)(q0 & 255) | ((unsigned)(q1 & 255) << 8) |
                ((unsigned)(q2 & 255) << 16) | ((unsigned)(q3 & 255) << 24);
  *(unsigned*)(qh + (size_t)t * DD + tid * 4) = pw;
}

// ------------- weight absmean: f64 partial sums, 20 matrices x 64 blocks --------------
// each thread streams 32 float4 (512B) through 4 independent accumulators
__global__ __launch_bounds__(256) void k_wabs_part(
    const float* __restrict__ w1s, const float* __restrict__ w2s,
    const float* __restrict__ w1r, const float* __restrict__ w2r,
    double* __restrict__ part) {
  __shared__ double red[4];
  int m = blockIdx.x >> 6, blk = blockIdx.x & 63;
  const float* base;
  if (m < 2)       base = w1s + (size_t)m * (DD * FF);
  else if (m < 4)  base = w2s + (size_t)(m - 2) * (DD * FF);
  else if (m < 12) base = w1r + (size_t)(m - 4) * (DD * FF);
  else             base = w2r + (size_t)(m - 12) * (DD * FF);
  const float4* p = (const float4*)base + (size_t)blk * 8192;
  int tid = threadIdx.x;
  double s0 = 0.0, s1 = 0.0, s2 = 0.0, s3 = 0.0;
#pragma unroll
  for (int i = 0; i < 8; ++i) {
    float4 va = p[tid + (i * 4 + 0) * 256];
    float4 vb = p[tid + (i * 4 + 1) * 256];
    float4 vc = p[tid + (i * 4 + 2) * 256];
    float4 vd = p[tid + (i * 4 + 3) * 256];
    s0 += (double)fabsf(va.x) + (double)fabsf(va.y) + (double)fabsf(va.z) + (double)fabsf(va.w);
    s1 += (double)fabsf(vb.x) + (double)fabsf(vb.y) + (double)fabsf(vb.z) + (double)fabsf(vb.w);
    s2 += (double)fabsf(vc.x) + (double)fabsf(vc.y) + (double)fabsf(vc.z) + (double)fabsf(vc.w);
    s3 += (double)fabsf(vd.x) + (double)fabsf(vd.y) + (double)fabsf(vd.z) + (double)fabsf(vd.w);
  }
  double s = (s0 + s1) + (s2 + s3);
  s = wave_sum_d(s);
  int lane = tid & 63, wid = tid >> 6;
  if (lane == 0) red[wid] = s;
  __syncthreads();
  if (tid == 0) part[m * 64 + blk] = red[0] + red[1] + red[2] + red[3];
}

__global__ __launch_bounds__(64) void k_wscale_final(
    const double* __restrict__ part, double* __restrict__ wscale) {
  int m = blockIdx.x;
  double v = part[m * 64 + threadIdx.x];
  v = wave_sum_d(v);
  if (threadIdx.x == 0) wscale[m] = v * (1.0 / 2097152.0) + 1e-8;
}

// ------------- router: bf16 products, f64 accum, bf16-rounded logits,
//               top-2 (lower-index tie-break), renorm -> dense gates + (i0,i1) ---------
__global__ __launch_bounds__(64) void k_router(
    const __hip_bfloat16* __restrict__ hb, const float* __restrict__ rw,
    float* __restrict__ gates, int2* __restrict__ i01) {
  int t = blockIdx.x, lane = threadIdx.x;
  double acc[8];
#pragma unroll
  for (int e = 0; e < 8; ++e) acc[e] = 0.0;
  const __hip_bfloat16* hp = hb + (size_t)t * DD;
  for (int d = lane; d < DD; d += 64) {
    double hv = (double)__bfloat162float(hp[d]);
#pragma unroll
    for (int e = 0; e < 8; ++e) {
      double wv = (double)__bfloat162float(__float2bfloat16(rw[e * DD + d]));
      acc[e] += hv * wv;
    }
  }
#pragma unroll
  for (int e = 0; e < 8; ++e) acc[e] = wave_sum_d(acc[e]);
  if (lane == 0) {
    double lb[8];
#pragma unroll
    for (int e = 0; e < 8; ++e)
      lb[e] = (double)__bfloat162float(__float2bfloat16((float)acc[e]));
    double mx = lb[0];
#pragma unroll
    for (int e = 1; e < 8; ++e) mx = fmax(mx, lb[e]);
    double p[8];
#pragma unroll
    for (int e = 0; e < 8; ++e) p[e] = exp(lb[e] - mx);
    int i0 = 0;
    for (int e = 1; e < 8; ++e) if (p[e] > p[i0]) i0 = e;
    int i1 = (i0 == 0) ? 1 : 0;
    for (int e = 0; e < 8; ++e) if (e != i0 && p[e] > p[i1]) i1 = e;
    double den = p[i0] + p[i1];
    float o[8] = {0.f, 0.f, 0.f, 0.f, 0.f, 0.f, 0.f, 0.f};
    o[i0] = (float)(p[i0] / den);
    o[i1] = (float)(p[i1] / den);
#pragma unroll
    for (int e = 0; e < 8; ++e) gates[(size_t)t * 8 + e] = o[e];
    i01[t] = make_int2(i0, i1);
  }
}

// ------------- per-expert ordered token lists (ballot prefix compaction) ---------------
__global__ __launch_bounds__(64) void k_lists(
    const int2* __restrict__ i01, int* __restrict__ lists,
    unsigned char* __restrict__ slots, int* __restrict__ cnt) {
  int e = blockIdx.x, lane = threadIdx.x;
  int* le = lists + e * TT;
  unsigned char* se = slots + e * TT;
  int base = 0;
  for (int it = 0; it < TT / 64; ++it) {
    int t = it * 64 + lane;
    int2 r = i01[t];
    bool hit0 = (r.x == e), hit1 = (r.y == e);
    bool hit = hit0 || hit1;
    unsigned long long m = __ballot(hit);
    int pos = base + __popcll(m & ((1ull << lane) - 1ull));
    if (hit) { le[pos] = t; se[pos] = hit0 ? 0 : 1; }
    base += __popcll(m);
  }
  if (lane == 0) cnt[e] = base;
}

// ------------- meta: segment offsets, tile->expert map, per-row gather tables ----------
__global__ __launch_bounds__(256) void k_meta(
    const int* __restrict__ cnt, const int* __restrict__ lists,
    const unsigned char* __restrict__ slots, const double* __restrict__ amax_clip,
    const double* __restrict__ wscale, int* __restrict__ meta,
    int* __restrict__ rowexp, int* __restrict__ tokidx,
    int* __restrict__ wrow, float* __restrict__ srow1c) {
  __shared__ int segs[9];
  __shared__ int scnt[8];
  int tid = threadIdx.x;
  if (tid == 0) {
    int acc = 0;
    for (int e = 0; e < 8; ++e) {
      scnt[e] = cnt[e];
      segs[e] = acc;
      acc += (cnt[e] + 127) & ~127;
    }
    segs[8] = acc;
    meta[0] = 32 + acc / 128;   // total row-tiles
    meta[1] = 4096 + acc;       // total compact rows
  }
  __syncthreads();
  int ntile = 32 + segs[8] / 128;
  for (int j = tid; j < NTILEMAX; j += 256) {
    int ei = -1;
    if (j < 16) ei = 0;
    else if (j < 32) ei = 1;
    else if (j < ntile) {
      int rr = (j - 32) * 128;
      for (int e = 0; e < 8; ++e)
        if (rr >= segs[e] && rr < segs[e + 1]) { ei = 2 + e; break; }
    }
    rowexp[j] = ei;
  }
  for (int r = tid; r < NRMAX; r += 256) {
    int t = 0; float s1 = 0.f; int w = -1;
    if (r < 4096) {
      int e = r >> 11; t = r & (TT - 1);
      double csc = wscale[e] * (1.0 / 127.0);
      s1 = (float)(amax_clip[t] * csc);
      w = e * TT + t;
    } else {
      int rr = r - 4096;
      if (rr < segs[8]) {
        int e = 0;
        for (int q = 0; q < 8; ++q)
          if (rr >= segs[q] && rr < segs[q + 1]) { e = q; break; }
        int k = rr - segs[e];
        if (k < scnt[e]) {
          t = lists[e * TT + k];
          int sl = slots[e * TT + k];
          double csc = wscale[4 + e] * (1.0 / 127.0);
          s1 = (float)(amax_clip[t] * csc);
          w = (2 + sl) * TT + t;
        }
      }
    }
    tokidx[r] = t; srow1c[r] = s1; wrow[r] = w;
  }
}

// ------------- ternary quant helper (f64 bins) -------------
__device__ __forceinline__ int qtern(float v, double winv) {
  double q = rint((double)v * winv);
  return (int)fmin(1.0, fmax(-1.0, q));
}
__device__ __forceinline__ unsigned pack4(int a, int b, int c, int d) {
  return (unsigned)(a & 255) | ((unsigned)(b & 255) << 8) |
         ((unsigned)(c & 255) << 16) | ((unsigned)(d & 255) << 24);
}

// ------------- weight quant + transpose: f32 [R][C] -> i8 W^T [C][R] -------------
__global__ __launch_bounds__(256) void k_wquant(
    const float* __restrict__ w1s, const float* __restrict__ w2s,
    const float* __restrict__ w1r, const float* __restrict__ w2r,
    const double* __restrict__ wscale,
    signed char* __restrict__ q1T, signed char* __restrict__ q2T) {
  __shared__ signed char tile[64 * 68];
  int bid = blockIdx.x;
  int m = bid >> 9, t = bid & 511;
  const float* src;
  signed char* dst;
  int ld, ldo, rt, ct;
  if (m < 2) {
    src = w1s + (size_t)m * DD * FF;
    dst = q1T + (size_t)m * FF * DD;
    ld = FF; ldo = DD; rt = t >> 5; ct = t & 31;
  } else if (m < 4) {
    src = w2s + (size_t)(m - 2) * FF * DD;
    dst = q2T + (size_t)(m - 2) * DD * FF;
    ld = DD; ldo = FF; rt = t >> 4; ct = t & 15;
  } else if (m < 12) {
    src = w1r + (size_t)(m - 4) * DD * FF;
    dst = q1T + (size_t)(m - 2) * FF * DD;
    ld = FF; ldo = DD; rt = t >> 5; ct = t & 31;
  } else {
    src = w2r + (size_t)(m - 12) * FF * DD;
    dst = q2T + (size_t)(m - 10) * DD * FF;
    ld = DD; ldo = FF; rt = t >> 4; ct = t & 15;
  }
  double winv = 1.0 / wscale[m];
  int row0 = rt * 64, col0 = ct * 64;
  int r = threadIdx.x >> 2, sc_ = (threadIdx.x & 3) * 16;
  const float* sp = src + (size_t)(row0 + r) * ld + col0 + sc_;
#pragma unroll
  for (int g = 0; g < 4; ++g) {
    float4 v = *(const float4*)(sp + g * 4);
    unsigned pk = pack4(qtern(v.x, winv), qtern(v.y, winv),
                        qtern(v.z, winv), qtern(v.w, winv));
    *(unsigned*)(tile + r * 68 + sc_ + g * 4) = pk;
  }
  __syncthreads();
  int c = threadIdx.x >> 2, sr = (threadIdx.x & 3) * 16;
  unsigned o[4];
#pragma unroll
  for (int g = 0; g < 4; ++g) {
    int j = sr + g * 4;
    o[g] = pack4(tile[(j + 0) * 68 + c], tile[(j + 1) * 68 + c],
                 tile[(j + 2) * 68 + c], tile[(j + 3) * 68 + c]);
  }
  int4 ov = make_int4((int)o[0], (int)o[1], (int)o[2], (int)o[3]);
  *(int4*)(dst + (size_t)(col0 + c) * ldo + row0 + sr) = ov;
}

// ------------- GEMM1 (compact rows, gathered A): 128x64 tiles -----------------------
// fixed grid (32, CHTILES) = 1152 blocks; bijective XCD swizzle (chunks of 144)
__global__ __launch_bounds__(256) void k_g1(
    const signed char* __restrict__ qh, const signed char* __restrict__ q1T,
    const int* __restrict__ rowexp, const int* __restrict__ tokidx,
    const float* __restrict__ srow1c, const int* __restrict__ meta, int tile0,
    float* __restrict__ abuf_c, unsigned* __restrict__ rowmaxc) {
  __shared__ __align__(16) signed char As[8192];   // 128 rows x 64 B
  __shared__ __align__(16) signed char Bs[4096];   // 64 rows x 64 B
  int lid = blockIdx.x + 32 * blockIdx.y;          // 0..1151
  int nid = (lid & 7) * 144 + (lid >> 3);          // bijective XCD chunks
  int j = tile0 + (nid >> 5);
  if (j >= meta[0]) return;
  int col0 = (nid & 31) * 64;
  int ei = rowexp[j];
  int tid = threadIdx.x, lane = tid & 63, wid = tid >> 6;
  int wr = wid >> 1, wc = wid & 1;
  int rowt0 = j * 128;
  // per-thread gathered A source pointers (k-invariant)
  int sub = lane >> 2, seg = (lane & 3) * 16;
  int sr0 = wid * 32 + sub, sr1 = sr0 + 16;
  const signed char* a0 = qh + (size_t)tokidx[rowt0 + sr0] * DD + seg;
  const signed char* a1 = qh + (size_t)tokidx[rowt0 + sr1] * DD + seg;
  const signed char* b_src = q1T + (size_t)ei * FF * DD + (size_t)col0 * DD;
  signed char* lda0 = As + (wid * 32) * 64;
  signed char* lda1 = As + (wid * 32 + 16) * 64;
  int kg = (lane >> 4) * 16, rsel = lane & 15;
  v4i zero = {0, 0, 0, 0};
  v4i acc[4][2];
#pragma unroll
  for (int i = 0; i < 4; ++i)
#pragma unroll
    for (int jj = 0; jj < 2; ++jj) acc[i][jj] = zero;
  for (int k0 = 0; k0 < DD; k0 += 64) {
    __syncthreads();
    gll16(a0 + k0, lda0);
    gll16(a1 + k0, lda1);
    stage_rows<64>(b_src + k0, DD, Bs, tid);
    __syncthreads();
    v4i af[4], bf[2];
#pragma unroll
    for (int mi = 0; mi < 4; ++mi)
      af[mi] = *(const v4i*)(As + (wr * 64 + mi * 16 + rsel) * 64 + kg);
#pragma unroll
    for (int ni = 0; ni < 2; ++ni)
      bf[ni] = *(const v4i*)(Bs + (wc * 32 + ni * 16 + rsel) * 64 + kg);
#pragma unroll
    for (int mi = 0; mi < 4; ++mi)
#pragma unroll
      for (int ni = 0; ni < 2; ++ni)
        acc[mi][ni] = __builtin_amdgcn_mfma_i32_16x16x64_i8(af[mi], bf[ni], acc[mi][ni], 0, 0, 0);
  }
  int rlocal0 = (j - tile0) * 128;
#pragma unroll
  for (int mi = 0; mi < 4; ++mi) {
#pragma unroll
    for (int rg = 0; rg < 4; ++rg) {
      int rof = wr * 64 + mi * 16 + ((lane >> 4) << 2) + rg;
      int tr = rowt0 + rof;
      float sA = srow1c[tr];
      float mloc = 0.f;
      int rl = rlocal0 + rof;
#pragma unroll
      for (int ni = 0; ni < 2; ++ni) {
        int fc = col0 + wc * 32 + ni * 16 + (lane & 15);
        float a = (float)acc[mi][ni][rg] * sA;
        float v = a / (1.f + expf(-a));
        abuf_c[(size_t)rl * FF + fc] = v;
        mloc = fmaxf(mloc, fabsf(v));
      }
#pragma unroll
      for (int o = 1; o < 16; o <<= 1) mloc = fmaxf(mloc, __shfl_xor(mloc, o));
      if ((lane & 15) == 0) atomicMax(rowmaxc + tr, __float_as_uint(mloc));
    }
  }
}

// ------------- aquant (chunk of compact rows) -------------
__global__ __launch_bounds__(256) void k_aq(
    const float* __restrict__ abuf_c, const unsigned* __restrict__ rowmaxc,
    const int* __restrict__ meta, int row0, signed char* __restrict__ qa) {
  int nrows = meta[1] - row0;
  if (nrows > CHROWS) nrows = CHROWS;
  if (nrows < 0) nrows = 0;
  int total4 = nrows * (FF / 4);
  int stride = gridDim.x * 256;
  for (int i = blockIdx.x * 256 + threadIdx.x; i < total4; i += stride) {
    int rl = i >> 9;
    int r = row0 + rl;
    float clip = fmaxf(__uint_as_float(rowmaxc[r]), 1e-5f);
    float s = 127.f / clip;
    float4 v = ((const float4*)abuf_c)[i];
    int q0 = (int)fminf(127.f, fmaxf(-128.f, rintf(v.x * s)));
    int q1 = (int)fminf(127.f, fmaxf(-128.f, rintf(v.y * s)));
    int q2 = (int)fminf(127.f, fmaxf(-128.f, rintf(v.z * s)));
    int q3 = (int)fminf(127.f, fmaxf(-128.f, rintf(v.w * s)));
    ((unsigned*)qa)[(size_t)r * (FF / 4) + (i & 511)] = pack4(q0, q1, q2, q3);
  }
}

// ------------- final gemm2 scale per compact row -------------
__global__ __launch_bounds__(256) void k_scg(
    const unsigned* __restrict__ rowmaxc, const double* __restrict__ wscale,
    const float* __restrict__ gates, const int* __restrict__ tokidx,
    const int* __restrict__ wrow, const int* __restrict__ rowexp,
    float* __restrict__ sgc) {
  int r = blockIdx.x * 256 + threadIdx.x;
  if (r >= NRMAX) return;
  int ei = rowexp[r >> 7];
  int w = wrow[r];
  if (ei < 0 || w < 0) { sgc[r] = 0.f; return; }
  float clip = fmaxf(__uint_as_float(rowmaxc[r]), 1e-5f);
  int t = tokidx[r];
  double csc = wscale[ei < 2 ? ei + 2 : ei + 10] * (1.0 / 127.0);
  float g = (ei < 2) ? 1.f : gates[(size_t)t * 8 + (ei - 2)];
  sgc[r] = (float)((double)clip * csc) * g;
}

// ------------- GEMM2 (compact rows): 128x64 tiles; pbuf[plane][t] = scaled row ------
// fixed grid (16, NTILEMAX) = 1152 blocks; bijective XCD swizzle (chunks of 144)
__global__ __launch_bounds__(256) void k_g2(
    const signed char* __restrict__ qa, const signed char* __restrict__ q2T,
    const int* __restrict__ rowexp, const float* __restrict__ sgc,
    const int* __restrict__ wrow, const int* __restrict__ meta,
    float* __restrict__ pbuf) {
  __shared__ __align__(16) signed char As[8192];   // 128 rows x 64 B
  __shared__ __align__(16) signed char Bs[4096];   // 64 rows x 64 B
  int lid = blockIdx.x + 16 * blockIdx.y;          // 0..1151
  int nid = (lid & 7) * 144 + (lid >> 3);
  int j = nid >> 4;
  if (j >= meta[0]) return;
  int col0 = (nid & 15) * 64;
  int ei = rowexp[j];
  int tid = threadIdx.x, lane = tid & 63, wid = tid >> 6;
  int wr = wid >> 1, wc = wid & 1;
  const signed char* ap = qa + (size_t)j * 128 * FF;
  const signed char* bp = q2T + (size_t)ei * DD * FF + (size_t)col0 * FF;
  int kg = (lane >> 4) * 16, rsel = lane & 15;
  v4i zero = {0, 0, 0, 0};
  v4i acc[4][2];
#pragma unroll
  for (int i = 0; i < 4; ++i)
#pragma unroll
    for (int jj = 0; jj < 2; ++jj) acc[i][jj] = zero;
  for (int k0 = 0; k0 < FF; k0 += 64) {
    __syncthreads();
    stage_rows<128>(ap + k0, FF, As, tid);
    stage_rows<64>(bp + k0, FF, Bs, tid);
    __syncthreads();
    v4i af[4], bf[2];
#pragma unroll
    for (int mi = 0; mi < 4; ++mi)
      af[mi] = *(const v4i*)(As + (wr * 64 + mi * 16 + rsel) * 64 + kg);
#pragma unroll
    for (int ni = 0; ni < 2; ++ni)
      bf[ni] = *(const v4i*)(Bs + (wc * 32 + ni * 16 + rsel) * 64 + kg);
#pragma unroll
    for (int mi = 0; mi < 4; ++mi)
#pragma unroll
      for (int ni = 0; ni < 2; ++ni)
        acc[mi][ni] = __builtin_amdgcn_mfma_i32_16x16x64_i8(af[mi], bf[ni], acc[mi][ni], 0, 0, 0);
  }
#pragma unroll
  for (int mi = 0; mi < 4; ++mi) {
#pragma unroll
    for (int rg = 0; rg < 4; ++rg) {
      int tr = j * 128 + wr * 64 + mi * 16 + ((lane >> 4) << 2) + rg;
      int w = wrow[tr];
      float sc = sgc[tr];
      if (w >= 0) {
#pragma unroll
        for (int ni = 0; ni < 2; ++ni) {
          int dc = col0 + wc * 32 + ni * 16 + (lane & 15);
          pbuf[(size_t)w * DD + dc] = (float)acc[mi][ni][rg] * sc;
        }
      }
    }
  }
}

// ------------- combine: out = sum of 4 planes -------------
__global__ __launch_bounds__(256) void k_combine(
    const float* __restrict__ pbuf, float* __restrict__ out) {
  int i = blockIdx.x * 256 + threadIdx.x;  // float4 index
  float4 s = ((const float4*)pbuf)[i];
#pragma unroll
  for (int z = 1; z < 4; ++z) {
    float4 v = ((const float4*)(pbuf + (size_t)z * TT * DD))[i];
    s.x += v.x; s.y += v.y; s.z += v.z; s.w += v.w;
  }
  ((float4*)out)[i] = s;
}

extern "C" void kernel_launch(void* const* d_in, const int* in_sizes, int n_in,
                              void* d_out, int out_size, void* d_ws, size_t ws_size,
                              hipStream_t stream) {
  const float* x    = (const float*)d_in[0];
  const float* rmsw = (const float*)d_in[1];
  const float* w1s  = (const float*)d_in[2];
  const float* w2s  = (const float*)d_in[3];
  const float* w1r  = (const float*)d_in[4];
  const float* w2r  = (const float*)d_in[5];
  const float* rw   = (const float*)d_in[6];
  float* out = (float*)d_out;

  char* ws = (char*)d_ws;
  // footprint ends at 0x7E80000 ~= 132.6MB (proven safe)
  double* amax_clip      = (double*)(ws + 0x0000000);   // 16KB
  double* part           = (double*)(ws + 0x0004000);   // 10KB (20*64 f64)
  double* wscale         = (double*)(ws + 0x0018000);   // 160B
  float* gates           = (float*)(ws + 0x0019000);    // 64KB
  int2* i01              = (int2*)(ws + 0x0029000);     // 16KB
  int* lists             = (int*)(ws + 0x002D000);      // 64KB
  unsigned char* slots   = (unsigned char*)(ws + 0x003D000); // 16KB
  int* cnt               = (int*)(ws + 0x0041000);      // 32B
  int* meta              = (int*)(ws + 0x0041100);      // 64B
  int* tokidx            = (int*)(ws + 0x0042000);      // 36KB
  int* wrow              = (int*)(ws + 0x004B000);      // 36KB
  float* srow1c          = (float*)(ws + 0x0054000);    // 36KB
  float* sgc             = (float*)(ws + 0x005D000);    // 36KB
  int* rowexp            = (int*)(ws + 0x0066000);      // 288B
  unsigned* rowmaxc      = (unsigned*)(ws + 0x0067000); // 36KB
  signed char* qh        = (signed char*)(ws + 0x0080000);    // 2MB
  __hip_bfloat16* hb     = (__hip_bfloat16*)(ws + 0x0280000); // 4MB
  signed char* q1T       = (signed char*)(ws + 0x0680000);    // 20MB
  signed char* q2T       = (signed char*)(ws + 0x1A80000);    // 20MB
  signed char* qa        = (signed char*)(ws + 0x2E80000);    // <=18.9MB (40MB region)
  float* pbuf            = (float*)(ws + 0x5680000);          // 4 planes = 32MB (40MB region)
  float* abuf_c          = pbuf;  // alias: chunk buffer (37.7MB) used before g2 writes pbuf

  k_zero<<<(NRMAX + 255) / 256, 256, 0, stream>>>(rowmaxc);
  k_rms_quant<<<TT, 256, 0, stream>>>(x, rmsw, qh, hb, amax_clip);
  k_wabs_part<<<20 * 64, 256, 0, stream>>>(w1s, w2s, w1r, w2r, part);
  k_wscale_final<<<20, 64, 0, stream>>>(part, wscale);
  k_router<<<TT, 64, 0, stream>>>(hb, rw, gates, i01);
  k_lists<<<8, 64, 0, stream>>>(i01, lists, slots, cnt);
  k_wquant<<<20 * 512, 256, 0, stream>>>(w1s, w2s, w1r, w2r, wscale, q1T, q2T);
  k_meta<<<1, 256, 0, stream>>>(cnt, lists, slots, amax_clip, wscale,
                                meta, rowexp, tokidx, wrow, srow1c);

  dim3 g1(32, CHTILES);
  k_g1<<<g1, 256, 0, stream>>>(qh, q1T, rowexp, tokidx, srow1c, meta, 0,
                               abuf_c, rowmaxc);
  k_aq<<<2048, 256, 0, stream>>>(abuf_c, rowmaxc, meta, 0, qa);
  k_g1<<<g1, 256, 0, stream>>>(qh, q1T, rowexp, tokidx, srow1c, meta, CHTILES,
                               abuf_c, rowmaxc);
  k_aq<<<2048, 256, 0, stream>>>(abuf_c, rowmaxc, meta, CHROWS, qa);

  k_scg<<<(NRMAX + 255) / 256, 256, 0, stream>>>(rowmaxc, wscale, gates,
                                                 tokidx, wrow, rowexp, sgc);
  dim3 g2(16, NTILEMAX);
  k_g2<<<g2, 256, 0, stream>>>(qa, q2T, rowexp, sgc, wrow, meta, pbuf);
  k_combine<<<TT * DD / 4 / 256, 256, 0, stream>>>(pbuf, out);
}